// Round 6
// baseline (685.985 us; speedup 1.0000x reference)
//
#include <hip/hip_runtime.h>
#include <math.h>

#define N_POS 100352   // 8*112*112
#define HW    12544    // 112*112

typedef unsigned short bf16_t;
typedef __attribute__((ext_vector_type(8))) short bf16x8;
typedef __attribute__((ext_vector_type(4))) float f32x4;

__device__ __forceinline__ bf16_t f2b(float f){
  unsigned u = __builtin_bit_cast(unsigned, f);
  unsigned r = (u + 0x7fffu + ((u >> 16) & 1u)) >> 16;
  return (bf16_t)r;
}
__device__ __forceinline__ float b2f(bf16_t h){
  unsigned u = ((unsigned)h) << 16;
  return __builtin_bit_cast(float, u);
}
__device__ __forceinline__ float blo(unsigned u){
  return __builtin_bit_cast(float, u << 16);
}
__device__ __forceinline__ float bhi(unsigned u){
  return __builtin_bit_cast(float, u & 0xffff0000u);
}

// ---------------- zero ----------------
__global__ void zero_kernel(float* p, int n){
  int i = blockIdx.x*256 + threadIdx.x;
  if (i < n) p[i] = 0.f;
}

// ---------------- weight transpose+cast: Wt[n][k] = bf16(W[k][n0+n]) ----------------
struct WJob { const float* src; bf16_t* dst; int K; int ldw; int n0; };
struct WJobs { WJob j[14]; };
__global__ void wtrans_kernel(WJobs js){
  WJob job = js.j[blockIdx.x];
  int t = threadIdx.x;
  int n = t & 63, k0 = t >> 6;
  for (int k = k0; k < job.K; k += 4)
    job.dst[(size_t)n*job.K + k] = f2b(job.src[(size_t)k*job.ldw + job.n0 + n]);
}

// ---------------- LayerNorm (128 ch) -> bf16 ----------------
__global__ __launch_bounds__(256) void ln128_kernel(const float* __restrict__ in,
    const float* __restrict__ w, const float* __restrict__ b, bf16_t* __restrict__ out){
  int row  = blockIdx.x*4 + (threadIdx.x >> 6);
  int lane = threadIdx.x & 63;
  const float* p = in + (size_t)row*128;
  float2 v = *(const float2*)(p + lane*2);
  float s = v.x + v.y;
  #pragma unroll
  for (int o = 1; o < 64; o <<= 1) s += __shfl_xor(s, o);
  float mu = s * (1.0f/128.0f);
  float dx = v.x - mu, dy = v.y - mu;
  float q = dx*dx + dy*dy;
  #pragma unroll
  for (int o = 1; o < 64; o <<= 1) q += __shfl_xor(q, o);
  float rs = rsqrtf(q * (1.0f/128.0f) + 1e-6f);
  int c = lane*2;
  ushort2 o2;
  o2.x = f2b(dx*rs*w[c]   + b[c]);
  o2.y = f2b(dy*rs*w[c+1] + b[c+1]);
  *(ushort2*)(out + (size_t)row*128 + c) = o2;
}

// ---------------- LayerNorm (64 ch) -> bf16 ----------------
__global__ __launch_bounds__(256) void ln64_kernel(const float* __restrict__ in,
    const float* __restrict__ w, const float* __restrict__ b, bf16_t* __restrict__ out){
  int row  = blockIdx.x*4 + (threadIdx.x >> 6);
  int lane = threadIdx.x & 63;
  float v = in[(size_t)row*64 + lane];
  float s = v;
  #pragma unroll
  for (int o = 1; o < 64; o <<= 1) s += __shfl_xor(s, o);
  float mu = s * (1.0f/64.0f);
  float d = v - mu;
  float q = d*d;
  #pragma unroll
  for (int o = 1; o < 64; o <<= 1) q += __shfl_xor(q, o);
  float rs = rsqrtf(q * (1.0f/64.0f) + 1e-6f);
  out[(size_t)row*64 + lane] = f2b(d*rs*w[lane] + b[lane]);
}

// ---------------- bf16 MFMA GEMM: 128x64 block, 4 waves x (32x64) ----------------
// 1D grid 8*T*98, XCD-bijective decode (A L2-shared across the T tiles of a
// row-block). 2-deep register pipeline: chunk k+1's global loads are issued
// BEFORE chunk k's regs are written to LDS, so they stay in flight across
// {LDS write, barrier, MFMA, barrier} -> exposed HBM latency per K-iter drops
// from ~900cy to the ~300cy compute span.
struct MTile {
  const bf16_t* Wt;    // [64][K] pre-transposed bf16
  const float* bias;
  void* out;           // bf16 or fp32 (out_fp32)
  const bf16_t* mult;  // optional gate, bf16 [row][ldm]
  int ldo; int ldm; int out_fp32;
};
struct MGemmParams {
  const bf16_t* A; const float* scale;
  int lda; int K; int rowsPerB; int ntiles;
  MTile tiles[8];
};

__global__ __launch_bounds__(256) void mgemm(MGemmParams p){
  __shared__ short As[128*72];
  __shared__ short Ws[64*72];
  const int tid = threadIdx.x;
  const int bid = blockIdx.x;
  const int xcd = bid & 7;
  const int j = bid >> 3;
  const int ti = j % p.ntiles;
  const int rb = (j / p.ntiles) * 8 + xcd;      // 0..783 (784 % 8 == 0)
  const MTile tile = p.tiles[ti];
  const int row0 = rb * 128;
  const int lane = tid & 63, wv = tid >> 6;
  const int wm = wv * 32;
  const int fm = lane & 15;
  const int quad = lane >> 4;
  f32x4 acc[2][4];
  #pragma unroll
  for (int mi = 0; mi < 2; mi++)
    #pragma unroll
    for (int ni = 0; ni < 4; ni++) acc[mi][ni] = (f32x4)0.f;
  const float* scale = p.scale ? (p.scale + (size_t)(row0 / p.rowsPerB) * p.K) : (const float*)0;

  const int sr = tid & 127, sq = tid >> 7;
  const int wn = tid & 63,  wq = tid >> 6;
  const bf16_t* srcA = p.A + (size_t)(row0 + sr)*p.lda + sq*32;
  const bf16_t* srcW = tile.Wt + (size_t)wn*p.K + wq*16;

  uint4 ra[4], rw[2];
  #pragma unroll
  for (int i = 0; i < 4; i++) ra[i] = *(const uint4*)(srcA + i*8);
  rw[0] = *(const uint4*)srcW;
  rw[1] = *(const uint4*)(srcW + 8);

  for (int k0 = 0; k0 < p.K; k0 += 64) {
    const bool more = (k0 + 64) < p.K;
    uint4 na[4], nw[2];
    if (more) {      // issue next chunk's loads (in flight across this iter)
      #pragma unroll
      for (int i = 0; i < 4; i++) na[i] = *(const uint4*)(srcA + k0 + 64 + i*8);
      nw[0] = *(const uint4*)(srcW + k0 + 64);
      nw[1] = *(const uint4*)(srcW + k0 + 64 + 8);
    }
    // write current chunk regs -> LDS (waits only on ra/rw)
    {
      short* dst = &As[sr*72 + sq*32];
      if (!scale) {
        #pragma unroll
        for (int i = 0; i < 4; i++) *(uint4*)(dst + i*8) = ra[i];
      } else {
        const float* sc = scale + k0 + sq*32;
        #pragma unroll
        for (int i = 0; i < 4; i++) {
          unsigned q4[4] = {ra[i].x, ra[i].y, ra[i].z, ra[i].w};
          #pragma unroll
          for (int jj = 0; jj < 4; jj++) {
            float lo = blo(q4[jj]) * sc[i*8 + jj*2];
            float hi = bhi(q4[jj]) * sc[i*8 + jj*2 + 1];
            unsigned o = (unsigned)f2b(lo) | ((unsigned)f2b(hi) << 16);
            *(unsigned*)(dst + i*8 + jj*2) = o;
          }
        }
      }
      short* dw = &Ws[wn*72 + wq*16];
      *(uint4*)dw       = rw[0];
      *(uint4*)(dw + 8) = rw[1];
    }
    __syncthreads();
    #pragma unroll
    for (int ks = 0; ks < 2; ks++) {
      int kb = ks*32 + quad*8;
      bf16x8 af0 = *(const bf16x8*)&As[(wm + fm)*72 + kb];
      bf16x8 af1 = *(const bf16x8*)&As[(wm + 16 + fm)*72 + kb];
      bf16x8 bfr[4];
      #pragma unroll
      for (int ni = 0; ni < 4; ni++) bfr[ni] = *(const bf16x8*)&Ws[(ni*16 + fm)*72 + kb];
      #pragma unroll
      for (int ni = 0; ni < 4; ni++) {
        acc[0][ni] = __builtin_amdgcn_mfma_f32_16x16x32_bf16(af0, bfr[ni], acc[0][ni], 0, 0, 0);
        acc[1][ni] = __builtin_amdgcn_mfma_f32_16x16x32_bf16(af1, bfr[ni], acc[1][ni], 0, 0, 0);
      }
    }
    __syncthreads();
    if (more) {
      #pragma unroll
      for (int i = 0; i < 4; i++) ra[i] = na[i];
      rw[0] = nw[0]; rw[1] = nw[1];
    }
  }
  #pragma unroll
  for (int mi = 0; mi < 2; mi++) {
    #pragma unroll
    for (int ni = 0; ni < 4; ni++) {
      int col = ni*16 + fm;
      float bias = tile.bias[col];
      #pragma unroll
      for (int r = 0; r < 4; r++) {
        int row = row0 + wm + mi*16 + quad*4 + r;
        float val = acc[mi][ni][r] + bias;
        if (tile.mult) val *= b2f(tile.mult[(size_t)row*tile.ldm + col]);
        if (tile.out_fp32) ((float*)tile.out)[(size_t)row*tile.ldo + col] = val;
        else ((bf16_t*)tile.out)[(size_t)row*tile.ldo + col] = f2b(val);
      }
    }
  }
}

// ---------------- 7x7 depthwise conv, 128 ch ----------------
__global__ __launch_bounds__(256) void dwconv128_kernel(const bf16_t* __restrict__ in,
    const float* __restrict__ cw, const float* __restrict__ cb, bf16_t* __restrict__ out){
  __shared__ float wsm[49*128];
  int t = threadIdx.x;
  // conflict-free staging: wave writes consecutive channels -> consecutive banks
  for (int i = t; i < 6272; i += 256) {
    int ch = i & 127, k = i >> 7;
    wsm[k*128 + ch] = cw[ch*49 + k];
  }
  __syncthreads();
  int c = (t & 63) * 2;               // channel pair base
  int wv = t >> 6;                    // 0..3 -> y pair
  int blk = blockIdx.x;               // 8 * 14 * 14
  int xs = blk % 14; int tmp = blk / 14;
  int yg = tmp % 14; int b = tmp / 14;
  int y0 = yg*8 + wv*2;               // outputs y0, y0+1
  int x0 = xs*8;
  float2 bias; bias.x = cb[c]; bias.y = cb[c+1];
  float2 acc0[8], acc1[8];
  #pragma unroll
  for (int i = 0; i < 8; i++) { acc0[i] = bias; acc1[i] = bias; }
  for (int r = 0; r < 8; r++) {
    int yy = y0 + r - 3;
    if ((unsigned)yy >= 112u) continue;          // wave-uniform
    const bf16_t* row = in + ((size_t)(b*112+yy)*112)*128 + c;
    unsigned u[14];
    #pragma unroll
    for (int i = 0; i < 14; i++) {
      int xx = x0 + i - 3;
      u[i] = ((unsigned)xx < 112u) ? *(const unsigned*)(row + (size_t)xx*128) : 0u;
    }
    float va[14], vb[14];
    #pragma unroll
    for (int i = 0; i < 14; i++) { va[i] = blo(u[i]); vb[i] = bhi(u[i]); }
    if (r < 7) {                                  // yout = y0, ky = r
      #pragma unroll
      for (int kx = 0; kx < 7; kx++) {
        float2 w = *(const float2*)&wsm[(r*7+kx)*128 + c];
        #pragma unroll
        for (int i = 0; i < 8; i++) {
          acc0[i].x = fmaf(w.x, va[i+kx], acc0[i].x);
          acc0[i].y = fmaf(w.y, vb[i+kx], acc0[i].y);
        }
      }
    }
    if (r >= 1) {                                 // yout = y0+1, ky = r-1
      #pragma unroll
      for (int kx = 0; kx < 7; kx++) {
        float2 w = *(const float2*)&wsm[((r-1)*7+kx)*128 + c];
        #pragma unroll
        for (int i = 0; i < 8; i++) {
          acc1[i].x = fmaf(w.x, va[i+kx], acc1[i].x);
          acc1[i].y = fmaf(w.y, vb[i+kx], acc1[i].y);
        }
      }
    }
  }
  size_t r0 = (size_t)(b*112+y0)*112 + x0;
  #pragma unroll
  for (int i = 0; i < 8; i++) {
    unsigned o0 = (unsigned)f2b(acc0[i].x) | ((unsigned)f2b(acc0[i].y) << 16);
    unsigned o1 = (unsigned)f2b(acc1[i].x) | ((unsigned)f2b(acc1[i].y) << 16);
    *(unsigned*)(out + (r0+i)*128 + c)       = o0;
    *(unsigned*)(out + (r0+112+i)*128 + c)   = o1;
  }
}

// ---------------- co/di fused dwconv, channel-paired, 2 output rows/thread ----------------
__global__ __launch_bounds__(256) void dwconv_codi_kernel(
    const bf16_t* __restrict__ rgb, const bf16_t* __restrict__ tb,
    const float* __restrict__ w1, const float* __restrict__ b1,
    const float* __restrict__ w2, const float* __restrict__ b2,
    bf16_t* __restrict__ out){
  __shared__ float wsm[49*128];   // [k][co 64 | di 64]
  int t = threadIdx.x;
  // conflict-free staging (consecutive channels -> consecutive banks)
  for (int i = t; i < 3136; i += 256) {
    int ch = i & 63, k = i >> 6;
    wsm[k*128 + ch]      = w1[ch*49 + k];
    wsm[k*128 + 64 + ch] = w2[ch*49 + k];
  }
  __syncthreads();
  int c = (t & 31) * 2;               // channel pair (of 64)
  int wv = t >> 5;                    // 0..7 -> y pair
  int blk = blockIdx.x;               // 8 * 7 * 14
  int xs = blk % 14; int tmp = blk / 14;
  int yg = tmp % 7; int b = tmp / 7;
  int y0 = yg*16 + wv*2;              // outputs y0, y0+1
  int x0 = xs*8;
  float2 bco; bco.x = b1[c]; bco.y = b1[c+1];
  float2 bdi; bdi.x = b2[c]; bdi.y = b2[c+1];
  float2 aco0[8], aco1[8], adi0[8], adi1[8];
  #pragma unroll
  for (int i = 0; i < 8; i++) { aco0[i] = bco; aco1[i] = bco; adi0[i] = bdi; adi1[i] = bdi; }
  for (int r = 0; r < 8; r++) {
    int yy = y0 + r - 3;
    if ((unsigned)yy >= 112u) continue;          // half-wave divergent at edges only
    const bf16_t* rrow = rgb + ((size_t)(b*112+yy)*112)*64 + c;
    const bf16_t* trow = tb  + ((size_t)(b*112+yy)*112)*64 + c;
    unsigned ru[14], tu[14];
    #pragma unroll
    for (int i = 0; i < 14; i++) {
      int xx = x0 + i - 3;
      bool ok = (unsigned)xx < 112u;
      ru[i] = ok ? *(const unsigned*)(rrow + (size_t)xx*64) : 0u;
      tu[i] = ok ? *(const unsigned*)(trow + (size_t)xx*64) : 0u;
    }
    float p0[14], p1[14], d0[14], d1[14];
    #pragma unroll
    for (int i = 0; i < 14; i++) {
      float a0 = blo(ru[i]), a1 = bhi(ru[i]);
      float t0 = blo(tu[i]), t1 = bhi(tu[i]);
      p0[i] = a0*t0; p1[i] = a1*t1;
      d0[i] = fabsf(a0-t0); d1[i] = fabsf(a1-t1);
    }
    if (r < 7) {                                  // yout = y0, ky = r
      #pragma unroll
      for (int kx = 0; kx < 7; kx++) {
        int k = r*7+kx;
        float2 wc = *(const float2*)&wsm[k*128 + c];
        float2 wd = *(const float2*)&wsm[k*128 + 64 + c];
        #pragma unroll
        for (int i = 0; i < 8; i++) {
          aco0[i].x = fmaf(wc.x, p0[i+kx], aco0[i].x);
          aco0[i].y = fmaf(wc.y, p1[i+kx], aco0[i].y);
          adi0[i].x = fmaf(wd.x, d0[i+kx], adi0[i].x);
          adi0[i].y = fmaf(wd.y, d1[i+kx], adi0[i].y);
        }
      }
    }
    if (r >= 1) {                                 // yout = y0+1, ky = r-1
      #pragma unroll
      for (int kx = 0; kx < 7; kx++) {
        int k = (r-1)*7+kx;
        float2 wc = *(const float2*)&wsm[k*128 + c];
        float2 wd = *(const float2*)&wsm[k*128 + 64 + c];
        #pragma unroll
        for (int i = 0; i < 8; i++) {
          aco1[i].x = fmaf(wc.x, p0[i+kx], aco1[i].x);
          aco1[i].y = fmaf(wc.y, p1[i+kx], aco1[i].y);
          adi1[i].x = fmaf(wd.x, d0[i+kx], adi1[i].x);
          adi1[i].y = fmaf(wd.y, d1[i+kx], adi1[i].y);
        }
      }
    }
  }
  size_t r0 = (size_t)(b*112+y0)*112 + x0;
  #pragma unroll
  for (int i = 0; i < 8; i++) {
    unsigned oc0 = (unsigned)f2b(aco0[i].x) | ((unsigned)f2b(aco0[i].y) << 16);
    unsigned od0 = (unsigned)f2b(adi0[i].x) | ((unsigned)f2b(adi0[i].y) << 16);
    unsigned oc1 = (unsigned)f2b(aco1[i].x) | ((unsigned)f2b(aco1[i].y) << 16);
    unsigned od1 = (unsigned)f2b(adi1[i].x) | ((unsigned)f2b(adi1[i].y) << 16);
    *(unsigned*)(out + (r0+i)*128 + c)            = oc0;
    *(unsigned*)(out + (r0+i)*128 + 64 + c)       = od0;
    *(unsigned*)(out + (r0+112+i)*128 + c)        = oc1;
    *(unsigned*)(out + (r0+112+i)*128 + 64 + c)   = od1;
  }
}

// ---------------- cosine-gate reductions (codi bf16) ----------------
__global__ __launch_bounds__(256) void reduce_kernel(const bf16_t* __restrict__ codi,
    float* __restrict__ dotb, float* __restrict__ n1sq, float* __restrict__ n2sq){
  int blk = blockIdx.x;          // 392
  int b = blk / 49, seg = blk % 49;
  int lane = threadIdx.x & 63, w = threadIdx.x >> 6;
  int c = lane*2;
  float d0=0,d1=0,s0=0,s1=0,a1=0;
  for (int i = 0; i < 64; i++) {
    int row = b*HW + seg*256 + w*64 + i;
    ushort2 v2 = *(const ushort2*)(codi + (size_t)row*128 + c);
    float vx = b2f(v2.x), vy = b2f(v2.y);
    float rs = vx + vy;
    #pragma unroll
    for (int o = 1; o < 64; o <<= 1) rs += __shfl_xor(rs, o);
    float amap = rs * (1.0f/128.0f);
    d0 += amap*vx; d1 += amap*vy;
    s0 += vx*vx;   s1 += vy*vy;
    if (lane == 0) a1 += amap*amap;
  }
  atomicAdd(&dotb[b*128+c],   d0); atomicAdd(&dotb[b*128+c+1], d1);
  atomicAdd(&n2sq[b*128+c],   s0); atomicAdd(&n2sq[b*128+c+1], s1);
  if (lane == 0) atomicAdd(&n1sq[b], a1);
}

__global__ __launch_bounds__(128) void attc_kernel(const float* __restrict__ dotb,
    const float* __restrict__ n1sq, const float* __restrict__ n2sq,
    const float* __restrict__ fc1, const float* __restrict__ fc2, float* __restrict__ attc){
  __shared__ float scos[128];
  __shared__ float sh[16];
  int t = threadIdx.x;
  int b = blockIdx.x;
  {
    float n1 = sqrtf(n1sq[b]);
    float n2 = sqrtf(n2sq[b*128+t]);
    scos[t] = dotb[b*128+t] / (n1*n2 + 1e-6f);
  }
  __syncthreads();
  if (t < 16) {
    float h = 0;
    for (int c = 0; c < 128; c++) h += scos[c]*fc1[c*16+t];
    sh[t] = h * 0.5f * (1.0f + erff(h*0.70710678118654752f));
  }
  __syncthreads();
  {
    float a = 0;
    for (int j = 0; j < 16; j++) a += sh[j]*fc2[j*128+t];
    attc[b*128+t] = 1.0f/(1.0f + __expf(-a));
  }
}

// ---------------- pooling (16x16 mean) of [xn|xen] (bf16) ----------------
__global__ void pool_kernel(const bf16_t* __restrict__ xn, const bf16_t* __restrict__ xen,
                            float* __restrict__ pool){
  int cellb = blockIdx.x;
  int py = blockIdx.y;
  int c = threadIdx.x;           // 0..191
  int b = cellb / 49, cell = cellb % 49;
  int wy = cell / 7, wx = cell % 7;
  float s = 0;
  for (int i = py*2; i < py*2+2; i++)
    for (int j = 0; j < 16; j++) {
      int y = wy*16+i, x = wx*16+j;
      size_t row = (size_t)(b*112+y)*112 + x;
      s += (c < 128) ? b2f(xn[row*128 + c]) : b2f(xen[row*64 + (c-128)]);
    }
  atomicAdd(&pool[(size_t)cellb*192 + c], s);
}

// ---------------- q projection ----------------
__global__ void qproj_kernel(const float* __restrict__ pool, const float* __restrict__ qw,
                             const float* __restrict__ qb, float* __restrict__ qbuf){
  int cellb = blockIdx.x;
  int j = threadIdx.x;
  float s = qb[j];
  for (int c = 0; c < 192; c++)
    s += pool[(size_t)cellb*192 + c] * (1.0f/256.0f) * qw[c*64 + j];
  qbuf[(size_t)cellb*64 + j] = s * 0.35355339059327373f;
}

// ---------------- flash attention split-K 16 (kv bf16) ----------------
__global__ __launch_bounds__(256) void attn_kernel(const float* __restrict__ qbuf,
    const bf16_t* __restrict__ kv, float* __restrict__ part){
  __shared__ float qs[392];
  __shared__ float ks[256*8];
  __shared__ float vs[256*8];
  int t = threadIdx.x;
  int blk = blockIdx.x;          // 1024 = b(8) * nh(8) * sp(16)
  int b = blk >> 7, nh = (blk >> 4) & 7, sp = blk & 15;
  for (int i = t; i < 392; i += 256)
    qs[i] = qbuf[(size_t)(b*49 + (i>>3))*64 + nh*8 + (i&7)];
  __syncthreads();
  int lane = t & 63, w = t >> 6;
  int qq = lane < 49 ? lane : 0;
  float4 qa = *(const float4*)&qs[qq*8];
  float4 qb4 = *(const float4*)&qs[qq*8+4];
  float m = -1e30f, l = 0.f;
  float4 acca = make_float4(0,0,0,0), accb = make_float4(0,0,0,0);
  const int base = sp * 784;
  uint4 kr, vr;
  {  // prefetch chunk 0 (all 256 threads valid: base+t < 12544)
    size_t rb = ((size_t)(b*HW + base + t))*128 + nh*8;
    kr = *(const uint4*)(kv + rb);
    vr = *(const uint4*)(kv + rb + 64);
  }
  for (int c0 = 0; c0 < 784; c0 += 256) {
    int cnt = 784 - c0 < 256 ? 784 - c0 : 256;
    __syncthreads();
    if (t < cnt) {
      const bf16_t* kp = (const bf16_t*)&kr;
      const bf16_t* vp = (const bf16_t*)&vr;
      float4 k0 = make_float4(b2f(kp[0]), b2f(kp[1]), b2f(kp[2]), b2f(kp[3]));
      float4 k1 = make_float4(b2f(kp[4]), b2f(kp[5]), b2f(kp[6]), b2f(kp[7]));
      float4 v0 = make_float4(b2f(vp[0]), b2f(vp[1]), b2f(vp[2]), b2f(vp[3]));
      float4 v1 = make_float4(b2f(vp[4]), b2f(vp[5]), b2f(vp[6]), b2f(vp[7]));
      *(float4*)&ks[t*8]   = k0; *(float4*)&ks[t*8+4] = k1;
      *(float4*)&vs[t*8]   = v0; *(float4*)&vs[t*8+4] = v1;
    }
    __syncthreads();
    // prefetch next chunk (loads in flight across the compute below)
    int c1 = c0 + 256;
    if (c1 < 784) {
      int cnt1 = 784 - c1 < 256 ? 784 - c1 : 256;
      if (t < cnt1) {
        size_t rb = ((size_t)(b*HW + base + c1 + t))*128 + nh*8;
        kr = *(const uint4*)(kv + rb);
        vr = *(const uint4*)(kv + rb + 64);
      }
    }
    int s0 = w*64;
    int n = cnt - s0; if (n < 0) n = 0; if (n > 64) n = 64;
    // n is always 0, 16, or 64 -> multiple of 16
    for (int i = 0; i < n; i += 16) {
      float s[16];
      #pragma unroll
      for (int j = 0; j < 16; j++) {
        const float* kp = &ks[(s0+i+j)*8];
        float4 ka = *(const float4*)kp, kb = *(const float4*)(kp+4);
        s[j] = qa.x*ka.x + qa.y*ka.y + qa.z*ka.z + qa.w*ka.w
             + qb4.x*kb.x + qb4.y*kb.y + qb4.z*kb.z + qb4.w*kb.w;
      }
      float t8[8];
      #pragma unroll
      for (int j = 0; j < 8; j++) t8[j] = fmaxf(s[2*j], s[2*j+1]);
      float t4a = fmaxf(t8[0], t8[1]), t4b = fmaxf(t8[2], t8[3]);
      float t4c = fmaxf(t8[4], t8[5]), t4d = fmaxf(t8[6], t8[7]);
      float mx = fmaxf(fmaxf(t4a, t4b), fmaxf(t4c, t4d));
      float mn = fmaxf(m, mx);
      float corr = __expf(m - mn);
      float p[16];
      #pragma unroll
      for (int j = 0; j < 16; j++) p[j] = __expf(s[j] - mn);
      float u8[8];
      #pragma unroll
      for (int j = 0; j < 8; j++) u8[j] = p[2*j] + p[2*j+1];
      float u4a = u8[0]+u8[1], u4b = u8[2]+u8[3], u4c = u8[4]+u8[5], u4d = u8[6]+u8[7];
      float lsum = (u4a+u4b) + (u4c+u4d);
      l = fmaf(l, corr, lsum);
      float4 sva = make_float4(0,0,0,0), svb = make_float4(0,0,0,0);
      #pragma unroll
      for (int j = 0; j < 16; j++) {
        const float* vp = &vs[(s0+i+j)*8];
        float4 va = *(const float4*)vp, vb = *(const float4*)(vp+4);
        sva.x = fmaf(p[j], va.x, sva.x); sva.y = fmaf(p[j], va.y, sva.y);
        sva.z = fmaf(p[j], va.z, sva.z); sva.w = fmaf(p[j], va.w, sva.w);
        svb.x = fmaf(p[j], vb.x, svb.x); svb.y = fmaf(p[j], vb.y, svb.y);
        svb.z = fmaf(p[j], vb.z, svb.z); svb.w = fmaf(p[j], vb.w, svb.w);
      }
      acca.x = fmaf(acca.x, corr, sva.x); acca.y = fmaf(acca.y, corr, sva.y);
      acca.z = fmaf(acca.z, corr, sva.z); acca.w = fmaf(acca.w, corr, sva.w);
      accb.x = fmaf(accb.x, corr, svb.x); accb.y = fmaf(accb.y, corr, svb.y);
      accb.z = fmaf(accb.z, corr, svb.z); accb.w = fmaf(accb.w, corr, svb.w);
      m = mn;
    }
  }
  // in-block merge of the 4 wave partials (reuse vs as scratch)
  __syncthreads();
  if (lane < 49) {
    float* rp = &vs[((size_t)w*49 + lane)*10];
    rp[0] = m; rp[1] = l;
    rp[2] = acca.x; rp[3] = acca.y; rp[4] = acca.z; rp[5] = acca.w;
    rp[6] = accb.x; rp[7] = accb.y; rp[8] = accb.z; rp[9] = accb.w;
  }
  __syncthreads();
  if (t < 49) {
    float M = -1e30f;
    #pragma unroll
    for (int w4 = 0; w4 < 4; w4++) M = fmaxf(M, vs[(w4*49 + t)*10]);
    float L = 0, a[8] = {0,0,0,0,0,0,0,0};
    #pragma unroll
    for (int w4 = 0; w4 < 4; w4++) {
      const float* rp = &vs[(w4*49 + t)*10];
      float c = __expf(rp[0] - M);
      L += rp[1]*c;
      #pragma unroll
      for (int d = 0; d < 8; d++) a[d] += rp[2+d]*c;
    }
    size_t idx = ((size_t)blk*49 + t)*10;
    part[idx] = M; part[idx+1] = L;
    #pragma unroll
    for (int d = 0; d < 8; d++) part[idx+2+d] = a[d];
  }
}

__global__ void merge_kernel(const float* __restrict__ part, float* __restrict__ gsm){
  int g = blockIdx.x*64 + threadIdx.x;   // 3136
  if (g >= 3136) return;
  int b = g / 392, r = g % 392, nh = r / 49, q = r % 49;
  int blkbase = b*128 + nh*16;
  float M = -1e30f;
  for (int sp = 0; sp < 16; sp++)
    M = fmaxf(M, part[((size_t)(blkbase+sp)*49 + q)*10]);
  float L = 0, a[8] = {0,0,0,0,0,0,0,0};
  for (int sp = 0; sp < 16; sp++) {
    size_t idx = ((size_t)(blkbase+sp)*49 + q)*10;
    float c = __expf(part[idx] - M);
    L += part[idx+1]*c;
    #pragma unroll
    for (int d = 0; d < 8; d++) a[d] += part[idx+2+d]*c;
  }
  #pragma unroll
  for (int d = 0; d < 8; d++)
    gsm[(size_t)(b*49+q)*64 + nh*8 + d] = a[d]/L;
}

// ---------------- xc cols 128..191: bilinear(g) -> bf16 ----------------
__global__ __launch_bounds__(256) void f2_kernel(const float* __restrict__ gsm,
                                                 bf16_t* __restrict__ xc){
  int gidx = blockIdx.x*256 + threadIdx.x;   // N*64 total
  int r = gidx >> 6, cc = gidx & 63;
  int b = r / HW, rem = r % HW, y = rem / 112, x = rem % 112;
  float fy = fminf(fmaxf((y + 0.5f)*0.0625f - 0.5f, 0.f), 6.f);
  float fx = fminf(fmaxf((x + 0.5f)*0.0625f - 0.5f, 0.f), 6.f);
  int y0 = (int)fy, x0 = (int)fx;
  float wy = fy - y0, wx = fx - x0;
  int y1 = y0+1 < 6 ? y0+1 : 6, x1 = x0+1 < 6 ? x0+1 : 6;
  const float* gb = gsm + (size_t)b*49*64 + cc;
  float g00 = gb[(y0*7+x0)*64], g01 = gb[(y0*7+x1)*64];
  float g10 = gb[(y1*7+x0)*64], g11 = gb[(y1*7+x1)*64];
  xc[(size_t)r*256 + 128 + cc] =
      f2b((1-wy)*((1-wx)*g00 + wx*g01) + wy*((1-wx)*g10 + wx*g11));
}

// =====================================================================
extern "C" void kernel_launch(void* const* d_in, const int* in_sizes, int n_in,
                              void* d_out, int out_size, void* d_ws, size_t ws_size,
                              hipStream_t stream) {
  const float* x      = (const float*)d_in[0];
  const float* x_e    = (const float*)d_in[1];
  const float* norm_w = (const float*)d_in[2];
  const float* norm_b = (const float*)d_in[3];
  const float* norme_w= (const float*)d_in[4];
  const float* norme_b= (const float*)d_in[5];
  const float* rr1_w  = (const float*)d_in[6];
  const float* rr1_b  = (const float*)d_in[7];
  const float* rr2_w  = (const float*)d_in[8];
  const float* rr2_b  = (const float*)d_in[9];
  const float* rr3_w  = (const float*)d_in[10];
  const float* rr3_b  = (const float*)d_in[11];
  const float* conv_w = (const float*)d_in[12];
  const float* conv_b = (const float*)d_in[13];
  const float* la1_w  = (const float*)d_in[14];
  const float* la1_b  = (const float*)d_in[15];
  const float* la2_w  = (const float*)d_in[16];
  const float* la2_b  = (const float*)d_in[17];
  const float* lac1_w = (const float*)d_in[18];
  const float* lac1_b = (const float*)d_in[19];
  const float* lac2_w = (const float*)d_in[20];
  const float* lac2_b = (const float*)d_in[21];
  const float* fc1_w  = (const float*)d_in[22];
  const float* fc2_w  = (const float*)d_in[23];
  const float* la3_w  = (const float*)d_in[24];
  const float* la3_b  = (const float*)d_in[25];
  const float* kv_w   = (const float*)d_in[26];
  const float* kv_b   = (const float*)d_in[27];
  const float* q_w    = (const float*)d_in[28];
  const float* q_b    = (const float*)d_in[29];
  const float* proj_w = (const float*)d_in[30];
  const float* proj_b = (const float*)d_in[31];
  const float* proje_w= (const float*)d_in[32];
  const float* proje_b= (const float*)d_in[33];

  const size_t N = N_POS;
  bf16_t* rr1   = (bf16_t*)d_ws;     // N*128 bf16, dead after G3
  bf16_t* xnbuf = rr1 + N*128;       // N*128: xn -> convout
  bf16_t* kvbuf = xnbuf + N*128;     // N*128: kv -> codi
  bf16_t* xcbuf = kvbuf + N*128;     // N*256: [rr2a | rgb | xen/t] -> xc
  float* pool = (float*)(xcbuf + N*256);  // 75264
  float* qbuf = pool + 75264;        // 25088
  float* part = qbuf + 25088;        // 1003520 (uses 501760)
  float* gsm  = part + 1003520;      // 25088
  float* dotb = gsm  + 25088;        // 1024
  float* n1sq = dotb + 1024;         // 8
  float* n2sq = n1sq + 8;            // 1024
  float* attc = n2sq + 1024;         // 1024
  bf16_t* wtab = (bf16_t*)(attc + 1024);  // 135168 shorts

  bf16_t* xn = xnbuf;
  bf16_t* convout = xnbuf;
  bf16_t* kv = kvbuf;
  bf16_t* codi = kvbuf;
  bf16_t* rr2a = xcbuf;
  bf16_t* rgb  = xcbuf + N*128;
  bf16_t* xen  = xcbuf + N*192;
  bf16_t* xc   = xcbuf;
  float* outp = (float*)d_out;
  float* oute = outp + N*128;

  bf16_t* rr1t0 = wtab;            bf16_t* rr1t1 = wtab + 8192;
  bf16_t* rr2t0 = wtab + 16384;    bf16_t* rr2t1 = wtab + 24576;
  bf16_t* la1t  = wtab + 32768;
  bf16_t* kvt0  = wtab + 40960;    bf16_t* kvt1  = wtab + 49152;
  bf16_t* la2t  = wtab + 57344;
  bf16_t* rr3t0 = wtab + 61440;    bf16_t* rr3t1 = wtab + 69632;
  bf16_t* la3t  = wtab + 77824;
  bf16_t* projt0= wtab + 86016;    bf16_t* projt1= wtab + 102400;
  bf16_t* projet= wtab + 118784;

  zero_kernel<<<(75264+255)/256, 256, 0, stream>>>(pool, 75264);
  zero_kernel<<<9, 256, 0, stream>>>(dotb, 2056);
  {
    WJobs js;
    js.j[0]  = {rr1_w,  rr1t0, 128, 128,   0};
    js.j[1]  = {rr1_w,  rr1t1, 128, 128,  64};
    js.j[2]  = {rr2_w,  rr2t0, 128, 128,   0};
    js.j[3]  = {rr2_w,  rr2t1, 128, 128,  64};
    js.j[4]  = {la1_w,  la1t,  128,  64,   0};
    js.j[5]  = {kv_w,   kvt0,  128, 128,   0};
    js.j[6]  = {kv_w,   kvt1,  128, 128,  64};
    js.j[7]  = {la2_w,  la2t,   64,  64,   0};
    js.j[8]  = {rr3_w,  rr3t0, 128, 128,   0};
    js.j[9]  = {rr3_w,  rr3t1, 128, 128,  64};
    js.j[10] = {la3_w,  la3t,  128,  64,   0};
    js.j[11] = {proj_w, projt0,256, 128,   0};
    js.j[12] = {proj_w, projt1,256, 128,  64};
    js.j[13] = {proje_w,projet,256,  64,   0};
    wtrans_kernel<<<14, 256, 0, stream>>>(js);
  }
  ln128_kernel<<<N_POS/4, 256, 0, stream>>>(x, norm_w, norm_b, xn);
  ln64_kernel <<<N_POS/4, 256, 0, stream>>>(x_e, norme_w, norme_b, xen);
  pool_kernel<<<dim3(392,8), 192, 0, stream>>>(xn, xen, pool);
  qproj_kernel<<<392, 64, 0, stream>>>(pool, q_w, q_b, qbuf);
  // G1: xn -> rr1 | rr2a | rgb | kv   (7 tiles, XCD-local)
  {
    MGemmParams p; p.A = xn; p.scale = 0; p.lda = 128; p.K = 128; p.rowsPerB = HW; p.ntiles = 7;
    p.tiles[0] = {rr1t0, rr1_b,    rr1,     0, 128, 0, 0};
    p.tiles[1] = {rr1t1, rr1_b+64, rr1+64,  0, 128, 0, 0};
    p.tiles[2] = {rr2t0, rr2_b,    rr2a,    0, 128, 0, 0};
    p.tiles[3] = {rr2t1, rr2_b+64, rr2a+64, 0, 128, 0, 0};
    p.tiles[4] = {la1t,  la1_b,    rgb,     0,  64, 0, 0};
    p.tiles[5] = {kvt0,  kv_b,     kv,      0, 128, 0, 0};
    p.tiles[6] = {kvt1,  kv_b+64,  kv+64,   0, 128, 0, 0};
    mgemm<<<8*7*98, 256, 0, stream>>>(p);
  }
  attn_kernel<<<1024, 256, 0, stream>>>(qbuf, kv, part);
  merge_kernel<<<49, 64, 0, stream>>>(part, gsm);
  // G2: xen -> t (in-place)
  {
    MGemmParams p; p.A = xen; p.scale = 0; p.lda = 64; p.K = 64; p.rowsPerB = HW; p.ntiles = 1;
    p.tiles[0] = {la2t, la2_b, xen, 0, 64, 0, 0};
    mgemm<<<8*1*98, 256, 0, stream>>>(p);
  }
  dwconv_codi_kernel<<<8*7*14, 256, 0, stream>>>(rgb, xen, lac1_w, lac1_b, lac2_w, lac2_b, codi);
  dwconv128_kernel<<<8*14*14, 256, 0, stream>>>(rr2a, conv_w, conv_b, convout);
  // G3: (convout@rr3 + b) * rr1 -> xc cols 0..127
  {
    MGemmParams p; p.A = convout; p.scale = 0; p.lda = 128; p.K = 128; p.rowsPerB = HW; p.ntiles = 2;
    p.tiles[0] = {rr3t0, rr3_b,    xc,    rr1,    256, 128, 0};
    p.tiles[1] = {rr3t1, rr3_b+64, xc+64, rr1+64, 256, 128, 0};
    mgemm<<<8*2*98, 256, 0, stream>>>(p);
  }
  reduce_kernel<<<392, 256, 0, stream>>>(codi, dotb, n1sq, n2sq);
  attc_kernel<<<8, 128, 0, stream>>>(dotb, n1sq, n2sq, fc1_w, fc2_w, attc);
  // G4: (codi * attc) @ la3 -> xc cols 192..255
  {
    MGemmParams p; p.A = codi; p.scale = attc; p.lda = 128; p.K = 128; p.rowsPerB = HW; p.ntiles = 1;
    p.tiles[0] = {la3t, la3_b, xc + 192, 0, 256, 0, 0};
    mgemm<<<8*1*98, 256, 0, stream>>>(p);
  }
  f2_kernel<<<25088, 256, 0, stream>>>(gsm, xc);
  // G5: xc -> out | out_e (fp32 outputs)
  {
    MGemmParams p; p.A = xc; p.scale = 0; p.lda = 256; p.K = 256; p.rowsPerB = HW; p.ntiles = 3;
    p.tiles[0] = {projt0, proj_b,    outp,    0, 128, 0, 1};
    p.tiles[1] = {projt1, proj_b+64, outp+64, 0, 128, 0, 1};
    p.tiles[2] = {projet, proje_b,   oute,    0,  64, 0, 1};
    mgemm<<<8*3*98, 256, 0, stream>>>(p);
  }
}

// Round 7
// 652.059 us; speedup vs baseline: 1.0520x; 1.0520x over previous
//
#include <hip/hip_runtime.h>
#include <math.h>

#define N_POS 100352   // 8*112*112
#define HW    12544    // 112*112

typedef unsigned short bf16_t;
typedef __attribute__((ext_vector_type(8))) short bf16x8;
typedef __attribute__((ext_vector_type(4))) float f32x4;

__device__ __forceinline__ bf16_t f2b(float f){
  unsigned u = __builtin_bit_cast(unsigned, f);
  unsigned r = (u + 0x7fffu + ((u >> 16) & 1u)) >> 16;
  return (bf16_t)r;
}
__device__ __forceinline__ float b2f(bf16_t h){
  unsigned u = ((unsigned)h) << 16;
  return __builtin_bit_cast(float, u);
}
__device__ __forceinline__ float blo(unsigned u){
  return __builtin_bit_cast(float, u << 16);
}
__device__ __forceinline__ float bhi(unsigned u){
  return __builtin_bit_cast(float, u & 0xffff0000u);
}

// ---------------- zero ----------------
__global__ void zero_kernel(float* p, int n){
  int i = blockIdx.x*256 + threadIdx.x;
  if (i < n) p[i] = 0.f;
}

// ---------------- weight transpose+cast: Wt[n][k] = bf16(W[k][n0+n]) ----------------
struct WJob { const float* src; bf16_t* dst; int K; int ldw; int n0; };
struct WJobs { WJob j[14]; };
__global__ void wtrans_kernel(WJobs js){
  WJob job = js.j[blockIdx.x];
  int t = threadIdx.x;
  int n = t & 63, k0 = t >> 6;
  for (int k = k0; k < job.K; k += 4)
    job.dst[(size_t)n*job.K + k] = f2b(job.src[(size_t)k*job.ldw + job.n0 + n]);
}

// ---------------- LayerNorm (128 ch) -> bf16 ----------------
__global__ __launch_bounds__(256) void ln128_kernel(const float* __restrict__ in,
    const float* __restrict__ w, const float* __restrict__ b, bf16_t* __restrict__ out){
  int row  = blockIdx.x*4 + (threadIdx.x >> 6);
  int lane = threadIdx.x & 63;
  const float* p = in + (size_t)row*128;
  float2 v = *(const float2*)(p + lane*2);
  float s = v.x + v.y;
  #pragma unroll
  for (int o = 1; o < 64; o <<= 1) s += __shfl_xor(s, o);
  float mu = s * (1.0f/128.0f);
  float dx = v.x - mu, dy = v.y - mu;
  float q = dx*dx + dy*dy;
  #pragma unroll
  for (int o = 1; o < 64; o <<= 1) q += __shfl_xor(q, o);
  float rs = rsqrtf(q * (1.0f/128.0f) + 1e-6f);
  int c = lane*2;
  ushort2 o2;
  o2.x = f2b(dx*rs*w[c]   + b[c]);
  o2.y = f2b(dy*rs*w[c+1] + b[c+1]);
  *(ushort2*)(out + (size_t)row*128 + c) = o2;
}

// ---------------- LayerNorm (64 ch) -> bf16 ----------------
__global__ __launch_bounds__(256) void ln64_kernel(const float* __restrict__ in,
    const float* __restrict__ w, const float* __restrict__ b, bf16_t* __restrict__ out){
  int row  = blockIdx.x*4 + (threadIdx.x >> 6);
  int lane = threadIdx.x & 63;
  float v = in[(size_t)row*64 + lane];
  float s = v;
  #pragma unroll
  for (int o = 1; o < 64; o <<= 1) s += __shfl_xor(s, o);
  float mu = s * (1.0f/64.0f);
  float d = v - mu;
  float q = d*d;
  #pragma unroll
  for (int o = 1; o < 64; o <<= 1) q += __shfl_xor(q, o);
  float rs = rsqrtf(q * (1.0f/64.0f) + 1e-6f);
  out[(size_t)row*64 + lane] = f2b(d*rs*w[lane] + b[lane]);
}

// ---------------- bf16 MFMA GEMM (64-col tiles): round-3 proven form ----------------
struct MTile {
  const bf16_t* Wt;    // pre-transposed bf16, rows = output cols
  const float* bias;
  void* out;           // bf16 or fp32 (out_fp32)
  const bf16_t* mult;  // optional gate, bf16 [row][ldm]
  int ldo; int ldm; int out_fp32;
};
struct MGemmParams {
  const bf16_t* A; const float* scale;
  int lda; int K; int rowsPerB; int ntiles;
  MTile tiles[8];
};

__global__ __launch_bounds__(256) void mgemm(MGemmParams p){
  __shared__ short As[128*72];
  __shared__ short Ws[64*72];
  const int tid = threadIdx.x;
  const int bid = blockIdx.x;
  const int xcd = bid & 7;
  const int j = bid >> 3;
  const int ti = j % p.ntiles;
  const int rb = (j / p.ntiles) * 8 + xcd;      // 0..783 (784 % 8 == 0)
  const MTile tile = p.tiles[ti];
  const int row0 = rb * 128;
  const int lane = tid & 63, wv = tid >> 6;
  const int wm = wv * 32;
  const int fm = lane & 15;
  const int quad = lane >> 4;
  f32x4 acc[2][4];
  #pragma unroll
  for (int mi = 0; mi < 2; mi++)
    #pragma unroll
    for (int ni = 0; ni < 4; ni++) acc[mi][ni] = (f32x4)0.f;
  const float* scale = p.scale ? (p.scale + (size_t)(row0 / p.rowsPerB) * p.K) : (const float*)0;

  const int sr = tid & 127, sq = tid >> 7;
  const int wn = tid & 63,  wq = tid >> 6;

  for (int k0 = 0; k0 < p.K; k0 += 64) {
    {
      const bf16_t* src = p.A + (size_t)(row0 + sr)*p.lda + k0 + sq*32;
      short* dst = &As[sr*72 + sq*32];
      if (!scale) {
        #pragma unroll
        for (int i = 0; i < 4; i++)
          *(uint4*)(dst + i*8) = *(const uint4*)(src + i*8);
      } else {
        const float* sc = scale + k0 + sq*32;
        #pragma unroll
        for (int i = 0; i < 32; i++) dst[i] = (short)f2b(b2f(src[i]) * sc[i]);
      }
    }
    {
      const bf16_t* src = tile.Wt + (size_t)wn*p.K + k0 + wq*16;
      short* dst = &Ws[wn*72 + wq*16];
      *(uint4*)dst       = *(const uint4*)src;
      *(uint4*)(dst + 8) = *(const uint4*)(src + 8);
    }
    __syncthreads();
    #pragma unroll
    for (int ks = 0; ks < 2; ks++) {
      int kb = ks*32 + quad*8;
      bf16x8 af0 = *(const bf16x8*)&As[(wm + fm)*72 + kb];
      bf16x8 af1 = *(const bf16x8*)&As[(wm + 16 + fm)*72 + kb];
      bf16x8 bfr[4];
      #pragma unroll
      for (int ni = 0; ni < 4; ni++) bfr[ni] = *(const bf16x8*)&Ws[(ni*16 + fm)*72 + kb];
      #pragma unroll
      for (int ni = 0; ni < 4; ni++) {
        acc[0][ni] = __builtin_amdgcn_mfma_f32_16x16x32_bf16(af0, bfr[ni], acc[0][ni], 0, 0, 0);
        acc[1][ni] = __builtin_amdgcn_mfma_f32_16x16x32_bf16(af1, bfr[ni], acc[1][ni], 0, 0, 0);
      }
    }
    __syncthreads();
  }
  #pragma unroll
  for (int mi = 0; mi < 2; mi++) {
    #pragma unroll
    for (int ni = 0; ni < 4; ni++) {
      int col = ni*16 + fm;
      float bias = tile.bias[col];
      #pragma unroll
      for (int r = 0; r < 4; r++) {
        int row = row0 + wm + mi*16 + quad*4 + r;
        float val = acc[mi][ni][r] + bias;
        if (tile.mult) val *= b2f(tile.mult[(size_t)row*tile.ldm + col]);
        if (tile.out_fp32) ((float*)tile.out)[(size_t)row*tile.ldo + col] = val;
        else ((bf16_t*)tile.out)[(size_t)row*tile.ldo + col] = f2b(val);
      }
    }
  }
}

// ---------------- 128-col variant: same schedule, double-wide W ----------------
// Wt is [128][K] (the t0/t1 pair is contiguous in wtab). One A-staging serves
// 128 output cols -> half the blocks/barriers per output byte, single
// contiguous write stream per block (preserves L2 write-merging).
__global__ __launch_bounds__(256) void mgemm_w128(MGemmParams p){
  __shared__ short As[128*72];
  __shared__ short Ws[128*72];
  const int tid = threadIdx.x;
  const int bid = blockIdx.x;
  const int xcd = bid & 7;
  const int j = bid >> 3;
  const int ti = j % p.ntiles;
  const int rb = (j / p.ntiles) * 8 + xcd;      // 0..783
  const MTile tile = p.tiles[ti];
  const int row0 = rb * 128;
  const int lane = tid & 63, wv = tid >> 6;
  const int wm = wv * 32;
  const int fm = lane & 15;
  const int quad = lane >> 4;
  f32x4 acc[2][8];
  #pragma unroll
  for (int mi = 0; mi < 2; mi++)
    #pragma unroll
    for (int ni = 0; ni < 8; ni++) acc[mi][ni] = (f32x4)0.f;

  const int sr = tid & 127, sq = tid >> 7;
  const int wn = tid & 63,  wq = tid >> 6;

  for (int k0 = 0; k0 < p.K; k0 += 64) {
    {
      const bf16_t* src = p.A + (size_t)(row0 + sr)*p.lda + k0 + sq*32;
      short* dst = &As[sr*72 + sq*32];
      #pragma unroll
      for (int i = 0; i < 4; i++)
        *(uint4*)(dst + i*8) = *(const uint4*)(src + i*8);
    }
    {
      const bf16_t* s0 = tile.Wt + (size_t)wn*p.K + k0 + wq*16;
      const bf16_t* s1 = tile.Wt + (size_t)(wn+64)*p.K + k0 + wq*16;
      short* d0 = &Ws[wn*72 + wq*16];
      short* d1 = &Ws[(wn+64)*72 + wq*16];
      *(uint4*)d0       = *(const uint4*)s0;
      *(uint4*)(d0 + 8) = *(const uint4*)(s0 + 8);
      *(uint4*)d1       = *(const uint4*)s1;
      *(uint4*)(d1 + 8) = *(const uint4*)(s1 + 8);
    }
    __syncthreads();
    #pragma unroll
    for (int ks = 0; ks < 2; ks++) {
      int kb = ks*32 + quad*8;
      bf16x8 af0 = *(const bf16x8*)&As[(wm + fm)*72 + kb];
      bf16x8 af1 = *(const bf16x8*)&As[(wm + 16 + fm)*72 + kb];
      #pragma unroll
      for (int ni = 0; ni < 8; ni++) {
        bf16x8 bfr = *(const bf16x8*)&Ws[(ni*16 + fm)*72 + kb];
        acc[0][ni] = __builtin_amdgcn_mfma_f32_16x16x32_bf16(af0, bfr, acc[0][ni], 0, 0, 0);
        acc[1][ni] = __builtin_amdgcn_mfma_f32_16x16x32_bf16(af1, bfr, acc[1][ni], 0, 0, 0);
      }
    }
    __syncthreads();
  }
  #pragma unroll
  for (int mi = 0; mi < 2; mi++) {
    #pragma unroll
    for (int ni = 0; ni < 8; ni++) {
      int col = ni*16 + fm;
      float bias = tile.bias[col];
      #pragma unroll
      for (int r = 0; r < 4; r++) {
        int row = row0 + wm + mi*16 + quad*4 + r;
        float val = acc[mi][ni][r] + bias;
        if (tile.mult) val *= b2f(tile.mult[(size_t)row*tile.ldm + col]);
        if (tile.out_fp32) ((float*)tile.out)[(size_t)row*tile.ldo + col] = val;
        else ((bf16_t*)tile.out)[(size_t)row*tile.ldo + col] = f2b(val);
      }
    }
  }
}

// ---------------- 7x7 depthwise conv, 128 ch ----------------
__global__ __launch_bounds__(256) void dwconv128_kernel(const bf16_t* __restrict__ in,
    const float* __restrict__ cw, const float* __restrict__ cb, bf16_t* __restrict__ out){
  __shared__ float wsm[49*128];
  int t = threadIdx.x;
  // conflict-free staging: wave writes consecutive channels -> consecutive banks
  for (int i = t; i < 6272; i += 256) {
    int ch = i & 127, k = i >> 7;
    wsm[k*128 + ch] = cw[ch*49 + k];
  }
  __syncthreads();
  int c = (t & 63) * 2;               // channel pair base
  int wv = t >> 6;                    // 0..3 -> y pair
  int blk = blockIdx.x;               // 8 * 14 * 14
  int xs = blk % 14; int tmp = blk / 14;
  int yg = tmp % 14; int b = tmp / 14;
  int y0 = yg*8 + wv*2;               // outputs y0, y0+1
  int x0 = xs*8;
  float2 bias; bias.x = cb[c]; bias.y = cb[c+1];
  float2 acc0[8], acc1[8];
  #pragma unroll
  for (int i = 0; i < 8; i++) { acc0[i] = bias; acc1[i] = bias; }
  for (int r = 0; r < 8; r++) {
    int yy = y0 + r - 3;
    if ((unsigned)yy >= 112u) continue;          // wave-uniform
    const bf16_t* row = in + ((size_t)(b*112+yy)*112)*128 + c;
    unsigned u[14];
    #pragma unroll
    for (int i = 0; i < 14; i++) {
      int xx = x0 + i - 3;
      u[i] = ((unsigned)xx < 112u) ? *(const unsigned*)(row + (size_t)xx*128) : 0u;
    }
    float va[14], vb[14];
    #pragma unroll
    for (int i = 0; i < 14; i++) { va[i] = blo(u[i]); vb[i] = bhi(u[i]); }
    if (r < 7) {                                  // yout = y0, ky = r
      #pragma unroll
      for (int kx = 0; kx < 7; kx++) {
        float2 w = *(const float2*)&wsm[(r*7+kx)*128 + c];
        #pragma unroll
        for (int i = 0; i < 8; i++) {
          acc0[i].x = fmaf(w.x, va[i+kx], acc0[i].x);
          acc0[i].y = fmaf(w.y, vb[i+kx], acc0[i].y);
        }
      }
    }
    if (r >= 1) {                                 // yout = y0+1, ky = r-1
      #pragma unroll
      for (int kx = 0; kx < 7; kx++) {
        float2 w = *(const float2*)&wsm[((r-1)*7+kx)*128 + c];
        #pragma unroll
        for (int i = 0; i < 8; i++) {
          acc1[i].x = fmaf(w.x, va[i+kx], acc1[i].x);
          acc1[i].y = fmaf(w.y, vb[i+kx], acc1[i].y);
        }
      }
    }
  }
  size_t r0 = (size_t)(b*112+y0)*112 + x0;
  #pragma unroll
  for (int i = 0; i < 8; i++) {
    unsigned o0 = (unsigned)f2b(acc0[i].x) | ((unsigned)f2b(acc0[i].y) << 16);
    unsigned o1 = (unsigned)f2b(acc1[i].x) | ((unsigned)f2b(acc1[i].y) << 16);
    *(unsigned*)(out + (r0+i)*128 + c)       = o0;
    *(unsigned*)(out + (r0+112+i)*128 + c)   = o1;
  }
}

// ---------------- co/di fused dwconv, channel-paired, 2 output rows/thread ----------------
__global__ __launch_bounds__(256) void dwconv_codi_kernel(
    const bf16_t* __restrict__ rgb, const bf16_t* __restrict__ tb,
    const float* __restrict__ w1, const float* __restrict__ b1,
    const float* __restrict__ w2, const float* __restrict__ b2,
    bf16_t* __restrict__ out){
  __shared__ float wsm[49*128];   // [k][co 64 | di 64]
  int t = threadIdx.x;
  // conflict-free staging (consecutive channels -> consecutive banks)
  for (int i = t; i < 3136; i += 256) {
    int ch = i & 63, k = i >> 6;
    wsm[k*128 + ch]      = w1[ch*49 + k];
    wsm[k*128 + 64 + ch] = w2[ch*49 + k];
  }
  __syncthreads();
  int c = (t & 31) * 2;               // channel pair (of 64)
  int wv = t >> 5;                    // 0..7 -> y pair
  int blk = blockIdx.x;               // 8 * 7 * 14
  int xs = blk % 14; int tmp = blk / 14;
  int yg = tmp % 7; int b = tmp / 7;
  int y0 = yg*16 + wv*2;              // outputs y0, y0+1
  int x0 = xs*8;
  float2 bco; bco.x = b1[c]; bco.y = b1[c+1];
  float2 bdi; bdi.x = b2[c]; bdi.y = b2[c+1];
  float2 aco0[8], aco1[8], adi0[8], adi1[8];
  #pragma unroll
  for (int i = 0; i < 8; i++) { aco0[i] = bco; aco1[i] = bco; adi0[i] = bdi; adi1[i] = bdi; }
  for (int r = 0; r < 8; r++) {
    int yy = y0 + r - 3;
    if ((unsigned)yy >= 112u) continue;          // half-wave divergent at edges only
    const bf16_t* rrow = rgb + ((size_t)(b*112+yy)*112)*64 + c;
    const bf16_t* trow = tb  + ((size_t)(b*112+yy)*112)*64 + c;
    unsigned ru[14], tu[14];
    #pragma unroll
    for (int i = 0; i < 14; i++) {
      int xx = x0 + i - 3;
      bool ok = (unsigned)xx < 112u;
      ru[i] = ok ? *(const unsigned*)(rrow + (size_t)xx*64) : 0u;
      tu[i] = ok ? *(const unsigned*)(trow + (size_t)xx*64) : 0u;
    }
    float p0[14], p1[14], d0[14], d1[14];
    #pragma unroll
    for (int i = 0; i < 14; i++) {
      float a0 = blo(ru[i]), a1 = bhi(ru[i]);
      float t0 = blo(tu[i]), t1 = bhi(tu[i]);
      p0[i] = a0*t0; p1[i] = a1*t1;
      d0[i] = fabsf(a0-t0); d1[i] = fabsf(a1-t1);
    }
    if (r < 7) {                                  // yout = y0, ky = r
      #pragma unroll
      for (int kx = 0; kx < 7; kx++) {
        int k = r*7+kx;
        float2 wc = *(const float2*)&wsm[k*128 + c];
        float2 wd = *(const float2*)&wsm[k*128 + 64 + c];
        #pragma unroll
        for (int i = 0; i < 8; i++) {
          aco0[i].x = fmaf(wc.x, p0[i+kx], aco0[i].x);
          aco0[i].y = fmaf(wc.y, p1[i+kx], aco0[i].y);
          adi0[i].x = fmaf(wd.x, d0[i+kx], adi0[i].x);
          adi0[i].y = fmaf(wd.y, d1[i+kx], adi0[i].y);
        }
      }
    }
    if (r >= 1) {                                 // yout = y0+1, ky = r-1
      #pragma unroll
      for (int kx = 0; kx < 7; kx++) {
        int k = (r-1)*7+kx;
        float2 wc = *(const float2*)&wsm[k*128 + c];
        float2 wd = *(const float2*)&wsm[k*128 + 64 + c];
        #pragma unroll
        for (int i = 0; i < 8; i++) {
          aco1[i].x = fmaf(wc.x, p0[i+kx], aco1[i].x);
          aco1[i].y = fmaf(wc.y, p1[i+kx], aco1[i].y);
          adi1[i].x = fmaf(wd.x, d0[i+kx], adi1[i].x);
          adi1[i].y = fmaf(wd.y, d1[i+kx], adi1[i].y);
        }
      }
    }
  }
  size_t r0 = (size_t)(b*112+y0)*112 + x0;
  #pragma unroll
  for (int i = 0; i < 8; i++) {
    unsigned oc0 = (unsigned)f2b(aco0[i].x) | ((unsigned)f2b(aco0[i].y) << 16);
    unsigned od0 = (unsigned)f2b(adi0[i].x) | ((unsigned)f2b(adi0[i].y) << 16);
    unsigned oc1 = (unsigned)f2b(aco1[i].x) | ((unsigned)f2b(aco1[i].y) << 16);
    unsigned od1 = (unsigned)f2b(adi1[i].x) | ((unsigned)f2b(adi1[i].y) << 16);
    *(unsigned*)(out + (r0+i)*128 + c)            = oc0;
    *(unsigned*)(out + (r0+i)*128 + 64 + c)       = od0;
    *(unsigned*)(out + (r0+112+i)*128 + c)        = oc1;
    *(unsigned*)(out + (r0+112+i)*128 + 64 + c)   = od1;
  }
}

// ---------------- cosine-gate reductions (codi bf16) ----------------
__global__ __launch_bounds__(256) void reduce_kernel(const bf16_t* __restrict__ codi,
    float* __restrict__ dotb, float* __restrict__ n1sq, float* __restrict__ n2sq){
  int blk = blockIdx.x;          // 392
  int b = blk / 49, seg = blk % 49;
  int lane = threadIdx.x & 63, w = threadIdx.x >> 6;
  int c = lane*2;
  float d0=0,d1=0,s0=0,s1=0,a1=0;
  for (int i = 0; i < 64; i++) {
    int row = b*HW + seg*256 + w*64 + i;
    ushort2 v2 = *(const ushort2*)(codi + (size_t)row*128 + c);
    float vx = b2f(v2.x), vy = b2f(v2.y);
    float rs = vx + vy;
    #pragma unroll
    for (int o = 1; o < 64; o <<= 1) rs += __shfl_xor(rs, o);
    float amap = rs * (1.0f/128.0f);
    d0 += amap*vx; d1 += amap*vy;
    s0 += vx*vx;   s1 += vy*vy;
    if (lane == 0) a1 += amap*amap;
  }
  atomicAdd(&dotb[b*128+c],   d0); atomicAdd(&dotb[b*128+c+1], d1);
  atomicAdd(&n2sq[b*128+c],   s0); atomicAdd(&n2sq[b*128+c+1], s1);
  if (lane == 0) atomicAdd(&n1sq[b], a1);
}

__global__ __launch_bounds__(128) void attc_kernel(const float* __restrict__ dotb,
    const float* __restrict__ n1sq, const float* __restrict__ n2sq,
    const float* __restrict__ fc1, const float* __restrict__ fc2, float* __restrict__ attc){
  __shared__ float scos[128];
  __shared__ float sh[16];
  int t = threadIdx.x;
  int b = blockIdx.x;
  {
    float n1 = sqrtf(n1sq[b]);
    float n2 = sqrtf(n2sq[b*128+t]);
    scos[t] = dotb[b*128+t] / (n1*n2 + 1e-6f);
  }
  __syncthreads();
  if (t < 16) {
    float h = 0;
    for (int c = 0; c < 128; c++) h += scos[c]*fc1[c*16+t];
    sh[t] = h * 0.5f * (1.0f + erff(h*0.70710678118654752f));
  }
  __syncthreads();
  {
    float a = 0;
    for (int j = 0; j < 16; j++) a += sh[j]*fc2[j*128+t];
    attc[b*128+t] = 1.0f/(1.0f + __expf(-a));
  }
}

// ---------------- pooling (16x16 mean) of [xn|xen] (bf16) ----------------
__global__ void pool_kernel(const bf16_t* __restrict__ xn, const bf16_t* __restrict__ xen,
                            float* __restrict__ pool){
  int cellb = blockIdx.x;
  int py = blockIdx.y;
  int c = threadIdx.x;           // 0..191
  int b = cellb / 49, cell = cellb % 49;
  int wy = cell / 7, wx = cell % 7;
  float s = 0;
  for (int i = py*2; i < py*2+2; i++)
    for (int j = 0; j < 16; j++) {
      int y = wy*16+i, x = wx*16+j;
      size_t row = (size_t)(b*112+y)*112 + x;
      s += (c < 128) ? b2f(xn[row*128 + c]) : b2f(xen[row*64 + (c-128)]);
    }
  atomicAdd(&pool[(size_t)cellb*192 + c], s);
}

// ---------------- q projection ----------------
__global__ void qproj_kernel(const float* __restrict__ pool, const float* __restrict__ qw,
                             const float* __restrict__ qb, float* __restrict__ qbuf){
  int cellb = blockIdx.x;
  int j = threadIdx.x;
  float s = qb[j];
  for (int c = 0; c < 192; c++)
    s += pool[(size_t)cellb*192 + c] * (1.0f/256.0f) * qw[c*64 + j];
  qbuf[(size_t)cellb*64 + j] = s * 0.35355339059327373f;
}

// ---------------- flash attention split-K 16 (kv bf16) ----------------
__global__ __launch_bounds__(256) void attn_kernel(const float* __restrict__ qbuf,
    const bf16_t* __restrict__ kv, float* __restrict__ part){
  __shared__ float qs[392];
  __shared__ float ks[256*8];
  __shared__ float vs[256*8];
  int t = threadIdx.x;
  int blk = blockIdx.x;          // 1024 = b(8) * nh(8) * sp(16)
  int b = blk >> 7, nh = (blk >> 4) & 7, sp = blk & 15;
  for (int i = t; i < 392; i += 256)
    qs[i] = qbuf[(size_t)(b*49 + (i>>3))*64 + nh*8 + (i&7)];
  __syncthreads();
  int lane = t & 63, w = t >> 6;
  int qq = lane < 49 ? lane : 0;
  float4 qa = *(const float4*)&qs[qq*8];
  float4 qb4 = *(const float4*)&qs[qq*8+4];
  float m = -1e30f, l = 0.f;
  float4 acca = make_float4(0,0,0,0), accb = make_float4(0,0,0,0);
  const int base = sp * 784;
  uint4 kr, vr;
  {  // prefetch chunk 0 (all 256 threads valid: base+t < 12544)
    size_t rb = ((size_t)(b*HW + base + t))*128 + nh*8;
    kr = *(const uint4*)(kv + rb);
    vr = *(const uint4*)(kv + rb + 64);
  }
  for (int c0 = 0; c0 < 784; c0 += 256) {
    int cnt = 784 - c0 < 256 ? 784 - c0 : 256;
    __syncthreads();
    if (t < cnt) {
      const bf16_t* kp = (const bf16_t*)&kr;
      const bf16_t* vp = (const bf16_t*)&vr;
      float4 k0 = make_float4(b2f(kp[0]), b2f(kp[1]), b2f(kp[2]), b2f(kp[3]));
      float4 k1 = make_float4(b2f(kp[4]), b2f(kp[5]), b2f(kp[6]), b2f(kp[7]));
      float4 v0 = make_float4(b2f(vp[0]), b2f(vp[1]), b2f(vp[2]), b2f(vp[3]));
      float4 v1 = make_float4(b2f(vp[4]), b2f(vp[5]), b2f(vp[6]), b2f(vp[7]));
      *(float4*)&ks[t*8]   = k0; *(float4*)&ks[t*8+4] = k1;
      *(float4*)&vs[t*8]   = v0; *(float4*)&vs[t*8+4] = v1;
    }
    __syncthreads();
    // prefetch next chunk (loads in flight across the compute below)
    int c1 = c0 + 256;
    if (c1 < 784) {
      int cnt1 = 784 - c1 < 256 ? 784 - c1 : 256;
      if (t < cnt1) {
        size_t rb = ((size_t)(b*HW + base + c1 + t))*128 + nh*8;
        kr = *(const uint4*)(kv + rb);
        vr = *(const uint4*)(kv + rb + 64);
      }
    }
    int s0 = w*64;
    int n = cnt - s0; if (n < 0) n = 0; if (n > 64) n = 64;
    // n is always 0, 16, or 64 -> multiple of 16
    for (int i = 0; i < n; i += 16) {
      float s[16];
      #pragma unroll
      for (int j = 0; j < 16; j++) {
        const float* kp = &ks[(s0+i+j)*8];
        float4 ka = *(const float4*)kp, kb = *(const float4*)(kp+4);
        s[j] = qa.x*ka.x + qa.y*ka.y + qa.z*ka.z + qa.w*ka.w
             + qb4.x*kb.x + qb4.y*kb.y + qb4.z*kb.z + qb4.w*kb.w;
      }
      float t8[8];
      #pragma unroll
      for (int j = 0; j < 8; j++) t8[j] = fmaxf(s[2*j], s[2*j+1]);
      float t4a = fmaxf(t8[0], t8[1]), t4b = fmaxf(t8[2], t8[3]);
      float t4c = fmaxf(t8[4], t8[5]), t4d = fmaxf(t8[6], t8[7]);
      float mx = fmaxf(fmaxf(t4a, t4b), fmaxf(t4c, t4d));
      float mn = fmaxf(m, mx);
      float corr = __expf(m - mn);
      float p[16];
      #pragma unroll
      for (int j = 0; j < 16; j++) p[j] = __expf(s[j] - mn);
      float u8[8];
      #pragma unroll
      for (int j = 0; j < 8; j++) u8[j] = p[2*j] + p[2*j+1];
      float u4a = u8[0]+u8[1], u4b = u8[2]+u8[3], u4c = u8[4]+u8[5], u4d = u8[6]+u8[7];
      float lsum = (u4a+u4b) + (u4c+u4d);
      l = fmaf(l, corr, lsum);
      float4 sva = make_float4(0,0,0,0), svb = make_float4(0,0,0,0);
      #pragma unroll
      for (int j = 0; j < 16; j++) {
        const float* vp = &vs[(s0+i+j)*8];
        float4 va = *(const float4*)vp, vb = *(const float4*)(vp+4);
        sva.x = fmaf(p[j], va.x, sva.x); sva.y = fmaf(p[j], va.y, sva.y);
        sva.z = fmaf(p[j], va.z, sva.z); sva.w = fmaf(p[j], va.w, sva.w);
        svb.x = fmaf(p[j], vb.x, svb.x); svb.y = fmaf(p[j], vb.y, svb.y);
        svb.z = fmaf(p[j], vb.z, svb.z); svb.w = fmaf(p[j], vb.w, svb.w);
      }
      acca.x = fmaf(acca.x, corr, sva.x); acca.y = fmaf(acca.y, corr, sva.y);
      acca.z = fmaf(acca.z, corr, sva.z); acca.w = fmaf(acca.w, corr, sva.w);
      accb.x = fmaf(accb.x, corr, svb.x); accb.y = fmaf(accb.y, corr, svb.y);
      accb.z = fmaf(accb.z, corr, svb.z); accb.w = fmaf(accb.w, corr, svb.w);
      m = mn;
    }
  }
  // in-block merge of the 4 wave partials (reuse vs as scratch)
  __syncthreads();
  if (lane < 49) {
    float* rp = &vs[((size_t)w*49 + lane)*10];
    rp[0] = m; rp[1] = l;
    rp[2] = acca.x; rp[3] = acca.y; rp[4] = acca.z; rp[5] = acca.w;
    rp[6] = accb.x; rp[7] = accb.y; rp[8] = accb.z; rp[9] = accb.w;
  }
  __syncthreads();
  if (t < 49) {
    float M = -1e30f;
    #pragma unroll
    for (int w4 = 0; w4 < 4; w4++) M = fmaxf(M, vs[(w4*49 + t)*10]);
    float L = 0, a[8] = {0,0,0,0,0,0,0,0};
    #pragma unroll
    for (int w4 = 0; w4 < 4; w4++) {
      const float* rp = &vs[(w4*49 + t)*10];
      float c = __expf(rp[0] - M);
      L += rp[1]*c;
      #pragma unroll
      for (int d = 0; d < 8; d++) a[d] += rp[2+d]*c;
    }
    size_t idx = ((size_t)blk*49 + t)*10;
    part[idx] = M; part[idx+1] = L;
    #pragma unroll
    for (int d = 0; d < 8; d++) part[idx+2+d] = a[d];
  }
}

__global__ void merge_kernel(const float* __restrict__ part, float* __restrict__ gsm){
  int g = blockIdx.x*64 + threadIdx.x;   // 3136
  if (g >= 3136) return;
  int b = g / 392, r = g % 392, nh = r / 49, q = r % 49;
  int blkbase = b*128 + nh*16;
  float M = -1e30f;
  for (int sp = 0; sp < 16; sp++)
    M = fmaxf(M, part[((size_t)(blkbase+sp)*49 + q)*10]);
  float L = 0, a[8] = {0,0,0,0,0,0,0,0};
  for (int sp = 0; sp < 16; sp++) {
    size_t idx = ((size_t)(blkbase+sp)*49 + q)*10;
    float c = __expf(part[idx] - M);
    L += part[idx+1]*c;
    #pragma unroll
    for (int d = 0; d < 8; d++) a[d] += part[idx+2+d]*c;
  }
  #pragma unroll
  for (int d = 0; d < 8; d++)
    gsm[(size_t)(b*49+q)*64 + nh*8 + d] = a[d]/L;
}

// ---------------- xc cols 128..191: bilinear(g) -> bf16 ----------------
__global__ __launch_bounds__(256) void f2_kernel(const float* __restrict__ gsm,
                                                 bf16_t* __restrict__ xc){
  int gidx = blockIdx.x*256 + threadIdx.x;   // N*64 total
  int r = gidx >> 6, cc = gidx & 63;
  int b = r / HW, rem = r % HW, y = rem / 112, x = rem % 112;
  float fy = fminf(fmaxf((y + 0.5f)*0.0625f - 0.5f, 0.f), 6.f);
  float fx = fminf(fmaxf((x + 0.5f)*0.0625f - 0.5f, 0.f), 6.f);
  int y0 = (int)fy, x0 = (int)fx;
  float wy = fy - y0, wx = fx - x0;
  int y1 = y0+1 < 6 ? y0+1 : 6, x1 = x0+1 < 6 ? x0+1 : 6;
  const float* gb = gsm + (size_t)b*49*64 + cc;
  float g00 = gb[(y0*7+x0)*64], g01 = gb[(y0*7+x1)*64];
  float g10 = gb[(y1*7+x0)*64], g11 = gb[(y1*7+x1)*64];
  xc[(size_t)r*256 + 128 + cc] =
      f2b((1-wy)*((1-wx)*g00 + wx*g01) + wy*((1-wx)*g10 + wx*g11));
}

// =====================================================================
extern "C" void kernel_launch(void* const* d_in, const int* in_sizes, int n_in,
                              void* d_out, int out_size, void* d_ws, size_t ws_size,
                              hipStream_t stream) {
  const float* x      = (const float*)d_in[0];
  const float* x_e    = (const float*)d_in[1];
  const float* norm_w = (const float*)d_in[2];
  const float* norm_b = (const float*)d_in[3];
  const float* norme_w= (const float*)d_in[4];
  const float* norme_b= (const float*)d_in[5];
  const float* rr1_w  = (const float*)d_in[6];
  const float* rr1_b  = (const float*)d_in[7];
  const float* rr2_w  = (const float*)d_in[8];
  const float* rr2_b  = (const float*)d_in[9];
  const float* rr3_w  = (const float*)d_in[10];
  const float* rr3_b  = (const float*)d_in[11];
  const float* conv_w = (const float*)d_in[12];
  const float* conv_b = (const float*)d_in[13];
  const float* la1_w  = (const float*)d_in[14];
  const float* la1_b  = (const float*)d_in[15];
  const float* la2_w  = (const float*)d_in[16];
  const float* la2_b  = (const float*)d_in[17];
  const float* lac1_w = (const float*)d_in[18];
  const float* lac1_b = (const float*)d_in[19];
  const float* lac2_w = (const float*)d_in[20];
  const float* lac2_b = (const float*)d_in[21];
  const float* fc1_w  = (const float*)d_in[22];
  const float* fc2_w  = (const float*)d_in[23];
  const float* la3_w  = (const float*)d_in[24];
  const float* la3_b  = (const float*)d_in[25];
  const float* kv_w   = (const float*)d_in[26];
  const float* kv_b   = (const float*)d_in[27];
  const float* q_w    = (const float*)d_in[28];
  const float* q_b    = (const float*)d_in[29];
  const float* proj_w = (const float*)d_in[30];
  const float* proj_b = (const float*)d_in[31];
  const float* proje_w= (const float*)d_in[32];
  const float* proje_b= (const float*)d_in[33];

  const size_t N = N_POS;
  bf16_t* rr1   = (bf16_t*)d_ws;     // N*128 bf16, dead after G3
  bf16_t* xnbuf = rr1 + N*128;       // N*128: xn -> convout
  bf16_t* kvbuf = xnbuf + N*128;     // N*128: kv -> codi
  bf16_t* xcbuf = kvbuf + N*128;     // N*256: [rr2a | rgb | xen/t] -> xc
  float* pool = (float*)(xcbuf + N*256);  // 75264
  float* qbuf = pool + 75264;        // 25088
  float* part = qbuf + 25088;        // 1003520 (uses 501760)
  float* gsm  = part + 1003520;      // 25088
  float* dotb = gsm  + 25088;        // 1024
  float* n1sq = dotb + 1024;         // 8
  float* n2sq = n1sq + 8;            // 1024
  float* attc = n2sq + 1024;         // 1024
  bf16_t* wtab = (bf16_t*)(attc + 1024);  // 135168 shorts

  bf16_t* xn = xnbuf;
  bf16_t* convout = xnbuf;
  bf16_t* kv = kvbuf;
  bf16_t* codi = kvbuf;
  bf16_t* rr2a = xcbuf;
  bf16_t* rgb  = xcbuf + N*128;
  bf16_t* xen  = xcbuf + N*192;
  bf16_t* xc   = xcbuf;
  float* outp = (float*)d_out;
  float* oute = outp + N*128;

  // t0/t1 pairs are contiguous -> each pair is a [128][K] table for mgemm_w128
  bf16_t* rr1t0 = wtab;            bf16_t* rr1t1 = wtab + 8192;
  bf16_t* rr2t0 = wtab + 16384;    bf16_t* rr2t1 = wtab + 24576;
  bf16_t* la1t  = wtab + 32768;
  bf16_t* kvt0  = wtab + 40960;    bf16_t* kvt1  = wtab + 49152;
  bf16_t* la2t  = wtab + 57344;
  bf16_t* rr3t0 = wtab + 61440;    bf16_t* rr3t1 = wtab + 69632;
  bf16_t* la3t  = wtab + 77824;
  bf16_t* projt0= wtab + 86016;    bf16_t* projt1= wtab + 102400;
  bf16_t* projet= wtab + 118784;

  zero_kernel<<<(75264+255)/256, 256, 0, stream>>>(pool, 75264);
  zero_kernel<<<9, 256, 0, stream>>>(dotb, 2056);
  {
    WJobs js;
    js.j[0]  = {rr1_w,  rr1t0, 128, 128,   0};
    js.j[1]  = {rr1_w,  rr1t1, 128, 128,  64};
    js.j[2]  = {rr2_w,  rr2t0, 128, 128,   0};
    js.j[3]  = {rr2_w,  rr2t1, 128, 128,  64};
    js.j[4]  = {la1_w,  la1t,  128,  64,   0};
    js.j[5]  = {kv_w,   kvt0,  128, 128,   0};
    js.j[6]  = {kv_w,   kvt1,  128, 128,  64};
    js.j[7]  = {la2_w,  la2t,   64,  64,   0};
    js.j[8]  = {rr3_w,  rr3t0, 128, 128,   0};
    js.j[9]  = {rr3_w,  rr3t1, 128, 128,  64};
    js.j[10] = {la3_w,  la3t,  128,  64,   0};
    js.j[11] = {proj_w, projt0,256, 128,   0};
    js.j[12] = {proj_w, projt1,256, 128,  64};
    js.j[13] = {proje_w,projet,256,  64,   0};
    wtrans_kernel<<<14, 256, 0, stream>>>(js);
  }
  ln128_kernel<<<N_POS/4, 256, 0, stream>>>(x, norm_w, norm_b, xn);
  ln64_kernel <<<N_POS/4, 256, 0, stream>>>(x_e, norme_w, norme_b, xen);
  pool_kernel<<<dim3(392,8), 192, 0, stream>>>(xn, xen, pool);
  qproj_kernel<<<392, 64, 0, stream>>>(pool, q_w, q_b, qbuf);
  // G1a: xn -> rr1 | rr2a | kv  (three 128-wide jobs, XCD-local)
  {
    MGemmParams p; p.A = xn; p.scale = 0; p.lda = 128; p.K = 128; p.rowsPerB = HW; p.ntiles = 3;
    p.tiles[0] = {rr1t0, rr1_b, rr1,  0, 128, 0, 0};
    p.tiles[1] = {rr2t0, rr2_b, rr2a, 0, 128, 0, 0};
    p.tiles[2] = {kvt0,  kv_b,  kv,   0, 128, 0, 0};
    mgemm_w128<<<8*3*98, 256, 0, stream>>>(p);
  }
  // G1b: xn -> rgb (la1, 64-wide)
  {
    MGemmParams p; p.A = xn; p.scale = 0; p.lda = 128; p.K = 128; p.rowsPerB = HW; p.ntiles = 1;
    p.tiles[0] = {la1t, la1_b, rgb, 0, 64, 0, 0};
    mgemm<<<8*1*98, 256, 0, stream>>>(p);
  }
  attn_kernel<<<1024, 256, 0, stream>>>(qbuf, kv, part);
  merge_kernel<<<49, 64, 0, stream>>>(part, gsm);
  // G2: xen -> t (in-place)
  {
    MGemmParams p; p.A = xen; p.scale = 0; p.lda = 64; p.K = 64; p.rowsPerB = HW; p.ntiles = 1;
    p.tiles[0] = {la2t, la2_b, xen, 0, 64, 0, 0};
    mgemm<<<8*1*98, 256, 0, stream>>>(p);
  }
  dwconv_codi_kernel<<<8*7*14, 256, 0, stream>>>(rgb, xen, lac1_w, lac1_b, lac2_w, lac2_b, codi);
  dwconv128_kernel<<<8*14*14, 256, 0, stream>>>(rr2a, conv_w, conv_b, convout);
  // G3: (convout@rr3 + b) * rr1 -> xc cols 0..127 (one 128-wide gated job)
  {
    MGemmParams p; p.A = convout; p.scale = 0; p.lda = 128; p.K = 128; p.rowsPerB = HW; p.ntiles = 1;
    p.tiles[0] = {rr3t0, rr3_b, xc, rr1, 256, 128, 0};
    mgemm_w128<<<8*1*98, 256, 0, stream>>>(p);
  }
  reduce_kernel<<<392, 256, 0, stream>>>(codi, dotb, n1sq, n2sq);
  attc_kernel<<<8, 128, 0, stream>>>(dotb, n1sq, n2sq, fc1_w, fc2_w, attc);
  // G4: (codi * attc) @ la3 -> xc cols 192..255
  {
    MGemmParams p; p.A = codi; p.scale = attc; p.lda = 128; p.K = 128; p.rowsPerB = HW; p.ntiles = 1;
    p.tiles[0] = {la3t, la3_b, xc + 192, 0, 256, 0, 0};
    mgemm<<<8*1*98, 256, 0, stream>>>(p);
  }
  f2_kernel<<<25088, 256, 0, stream>>>(gsm, xc);
  // G5a: xc -> out (proj, 128-wide fp32)
  {
    MGemmParams p; p.A = xc; p.scale = 0; p.lda = 256; p.K = 256; p.rowsPerB = HW; p.ntiles = 1;
    p.tiles[0] = {projt0, proj_b, outp, 0, 128, 0, 1};
    mgemm_w128<<<8*1*98, 256, 0, stream>>>(p);
  }
  // G5b: xc -> out_e (proje, 64-wide fp32)
  {
    MGemmParams p; p.A = xc; p.scale = 0; p.lda = 256; p.K = 256; p.rowsPerB = HW; p.ntiles = 1;
    p.tiles[0] = {projet, proje_b, oute, 0, 64, 0, 1};
    mgemm<<<8*1*98, 256, 0, stream>>>(p);
  }
}

// Round 8
// 596.727 us; speedup vs baseline: 1.1496x; 1.0927x over previous
//
#include <hip/hip_runtime.h>
#include <math.h>

#define N_POS 100352   // 8*112*112
#define HW    12544    // 112*112

typedef unsigned short bf16_t;
typedef __attribute__((ext_vector_type(8))) short bf16x8;
typedef __attribute__((ext_vector_type(4))) float f32x4;

__device__ __forceinline__ bf16_t f2b(float f){
  unsigned u = __builtin_bit_cast(unsigned, f);
  unsigned r = (u + 0x7fffu + ((u >> 16) & 1u)) >> 16;
  return (bf16_t)r;
}
__device__ __forceinline__ float b2f(bf16_t h){
  unsigned u = ((unsigned)h) << 16;
  return __builtin_bit_cast(float, u);
}
__device__ __forceinline__ float blo(unsigned u){
  return __builtin_bit_cast(float, u << 16);
}
__device__ __forceinline__ float bhi(unsigned u){
  return __builtin_bit_cast(float, u & 0xffff0000u);
}

// ---------------- zero ----------------
__global__ void zero_kernel(float* p, int n){
  int i = blockIdx.x*256 + threadIdx.x;
  if (i < n) p[i] = 0.f;
}

// ---------------- weight transpose+cast: Wt[n][k] = bf16(W[k][n0+n]) ----------------
struct WJob { const float* src; bf16_t* dst; int K; int ldw; int n0; };
struct WJobs { WJob j[14]; };
__global__ void wtrans_kernel(WJobs js){
  WJob job = js.j[blockIdx.x];
  int t = threadIdx.x;
  int n = t & 63, k0 = t >> 6;
  for (int k = k0; k < job.K; k += 4)
    job.dst[(size_t)n*job.K + k] = f2b(job.src[(size_t)k*job.ldw + job.n0 + n]);
}

// ---------------- LayerNorm (128 ch) -> bf16 ----------------
__global__ __launch_bounds__(256) void ln128_kernel(const float* __restrict__ in,
    const float* __restrict__ w, const float* __restrict__ b, bf16_t* __restrict__ out){
  int row  = blockIdx.x*4 + (threadIdx.x >> 6);
  int lane = threadIdx.x & 63;
  const float* p = in + (size_t)row*128;
  float2 v = *(const float2*)(p + lane*2);
  float s = v.x + v.y;
  #pragma unroll
  for (int o = 1; o < 64; o <<= 1) s += __shfl_xor(s, o);
  float mu = s * (1.0f/128.0f);
  float dx = v.x - mu, dy = v.y - mu;
  float q = dx*dx + dy*dy;
  #pragma unroll
  for (int o = 1; o < 64; o <<= 1) q += __shfl_xor(q, o);
  float rs = rsqrtf(q * (1.0f/128.0f) + 1e-6f);
  int c = lane*2;
  ushort2 o2;
  o2.x = f2b(dx*rs*w[c]   + b[c]);
  o2.y = f2b(dy*rs*w[c+1] + b[c+1]);
  *(ushort2*)(out + (size_t)row*128 + c) = o2;
}

// ---------------- LayerNorm (64 ch) -> bf16 ----------------
__global__ __launch_bounds__(256) void ln64_kernel(const float* __restrict__ in,
    const float* __restrict__ w, const float* __restrict__ b, bf16_t* __restrict__ out){
  int row  = blockIdx.x*4 + (threadIdx.x >> 6);
  int lane = threadIdx.x & 63;
  float v = in[(size_t)row*64 + lane];
  float s = v;
  #pragma unroll
  for (int o = 1; o < 64; o <<= 1) s += __shfl_xor(s, o);
  float mu = s * (1.0f/64.0f);
  float d = v - mu;
  float q = d*d;
  #pragma unroll
  for (int o = 1; o < 64; o <<= 1) q += __shfl_xor(q, o);
  float rs = rsqrtf(q * (1.0f/64.0f) + 1e-6f);
  out[(size_t)row*64 + lane] = f2b(d*rs*w[lane] + b[lane]);
}

// ---------------- bf16 MFMA GEMM: 128x64 block, 4 waves x (32x64) ----------------
// Round-3 proven form (FROZEN): 1D grid 8*T*98, XCD-bijective decode.
// Measured: restructures that reduce resident-block count (multi-tile r4,
// reg-pipeline r6, w128 r7) all regress -- latency hiding via many blocks
// plus L2 write-merging is the winning regime for these thin GEMMs.
struct MTile {
  const bf16_t* Wt;    // [64][K] pre-transposed bf16
  const float* bias;
  void* out;           // bf16 or fp32 (out_fp32)
  const bf16_t* mult;  // optional gate, bf16 [row][ldm]
  int ldo; int ldm; int out_fp32;
};
struct MGemmParams {
  const bf16_t* A; const float* scale;
  int lda; int K; int rowsPerB; int ntiles;
  MTile tiles[8];
};

__global__ __launch_bounds__(256) void mgemm(MGemmParams p){
  __shared__ short As[128*72];
  __shared__ short Ws[64*72];
  const int tid = threadIdx.x;
  const int bid = blockIdx.x;
  const int xcd = bid & 7;
  const int j = bid >> 3;
  const int ti = j % p.ntiles;
  const int rb = (j / p.ntiles) * 8 + xcd;      // 0..783 (784 % 8 == 0)
  const MTile tile = p.tiles[ti];
  const int row0 = rb * 128;
  const int lane = tid & 63, wv = tid >> 6;
  const int wm = wv * 32;
  const int fm = lane & 15;
  const int quad = lane >> 4;
  f32x4 acc[2][4];
  #pragma unroll
  for (int mi = 0; mi < 2; mi++)
    #pragma unroll
    for (int ni = 0; ni < 4; ni++) acc[mi][ni] = (f32x4)0.f;
  const float* scale = p.scale ? (p.scale + (size_t)(row0 / p.rowsPerB) * p.K) : (const float*)0;

  const int sr = tid & 127, sq = tid >> 7;
  const int wn = tid & 63,  wq = tid >> 6;

  for (int k0 = 0; k0 < p.K; k0 += 64) {
    {
      const bf16_t* src = p.A + (size_t)(row0 + sr)*p.lda + k0 + sq*32;
      short* dst = &As[sr*72 + sq*32];
      if (!scale) {
        #pragma unroll
        for (int i = 0; i < 4; i++)
          *(uint4*)(dst + i*8) = *(const uint4*)(src + i*8);
      } else {
        const float* sc = scale + k0 + sq*32;
        #pragma unroll
        for (int i = 0; i < 32; i++) dst[i] = (short)f2b(b2f(src[i]) * sc[i]);
      }
    }
    {
      const bf16_t* src = tile.Wt + (size_t)wn*p.K + k0 + wq*16;
      short* dst = &Ws[wn*72 + wq*16];
      *(uint4*)dst       = *(const uint4*)src;
      *(uint4*)(dst + 8) = *(const uint4*)(src + 8);
    }
    __syncthreads();
    #pragma unroll
    for (int ks = 0; ks < 2; ks++) {
      int kb = ks*32 + quad*8;
      bf16x8 af0 = *(const bf16x8*)&As[(wm + fm)*72 + kb];
      bf16x8 af1 = *(const bf16x8*)&As[(wm + 16 + fm)*72 + kb];
      bf16x8 bfr[4];
      #pragma unroll
      for (int ni = 0; ni < 4; ni++) bfr[ni] = *(const bf16x8*)&Ws[(ni*16 + fm)*72 + kb];
      #pragma unroll
      for (int ni = 0; ni < 4; ni++) {
        acc[0][ni] = __builtin_amdgcn_mfma_f32_16x16x32_bf16(af0, bfr[ni], acc[0][ni], 0, 0, 0);
        acc[1][ni] = __builtin_amdgcn_mfma_f32_16x16x32_bf16(af1, bfr[ni], acc[1][ni], 0, 0, 0);
      }
    }
    __syncthreads();
  }
  #pragma unroll
  for (int mi = 0; mi < 2; mi++) {
    #pragma unroll
    for (int ni = 0; ni < 4; ni++) {
      int col = ni*16 + fm;
      float bias = tile.bias[col];
      #pragma unroll
      for (int r = 0; r < 4; r++) {
        int row = row0 + wm + mi*16 + quad*4 + r;
        float val = acc[mi][ni][r] + bias;
        if (tile.mult) val *= b2f(tile.mult[(size_t)row*tile.ldm + col]);
        if (tile.out_fp32) ((float*)tile.out)[(size_t)row*tile.ldo + col] = val;
        else ((bf16_t*)tile.out)[(size_t)row*tile.ldo + col] = f2b(val);
      }
    }
  }
}

// ---------------- 7x7 depthwise conv, 128 ch ----------------
__global__ __launch_bounds__(256) void dwconv128_kernel(const bf16_t* __restrict__ in,
    const float* __restrict__ cw, const float* __restrict__ cb, bf16_t* __restrict__ out){
  __shared__ float wsm[49*128];
  int t = threadIdx.x;
  // conflict-free staging: wave writes consecutive channels -> consecutive banks
  for (int i = t; i < 6272; i += 256) {
    int ch = i & 127, k = i >> 7;
    wsm[k*128 + ch] = cw[ch*49 + k];
  }
  __syncthreads();
  int c = (t & 63) * 2;               // channel pair base
  int wv = t >> 6;                    // 0..3 -> y pair
  int blk = blockIdx.x;               // 8 * 14 * 14
  int xs = blk % 14; int tmp = blk / 14;
  int yg = tmp % 14; int b = tmp / 14;
  int y0 = yg*8 + wv*2;               // outputs y0, y0+1
  int x0 = xs*8;
  float2 bias; bias.x = cb[c]; bias.y = cb[c+1];
  float2 acc0[8], acc1[8];
  #pragma unroll
  for (int i = 0; i < 8; i++) { acc0[i] = bias; acc1[i] = bias; }
  for (int r = 0; r < 8; r++) {
    int yy = y0 + r - 3;
    if ((unsigned)yy >= 112u) continue;          // wave-uniform
    const bf16_t* row = in + ((size_t)(b*112+yy)*112)*128 + c;
    unsigned u[14];
    #pragma unroll
    for (int i = 0; i < 14; i++) {
      int xx = x0 + i - 3;
      u[i] = ((unsigned)xx < 112u) ? *(const unsigned*)(row + (size_t)xx*128) : 0u;
    }
    float va[14], vb[14];
    #pragma unroll
    for (int i = 0; i < 14; i++) { va[i] = blo(u[i]); vb[i] = bhi(u[i]); }
    if (r < 7) {                                  // yout = y0, ky = r
      #pragma unroll
      for (int kx = 0; kx < 7; kx++) {
        float2 w = *(const float2*)&wsm[(r*7+kx)*128 + c];
        #pragma unroll
        for (int i = 0; i < 8; i++) {
          acc0[i].x = fmaf(w.x, va[i+kx], acc0[i].x);
          acc0[i].y = fmaf(w.y, vb[i+kx], acc0[i].y);
        }
      }
    }
    if (r >= 1) {                                 // yout = y0+1, ky = r-1
      #pragma unroll
      for (int kx = 0; kx < 7; kx++) {
        float2 w = *(const float2*)&wsm[((r-1)*7+kx)*128 + c];
        #pragma unroll
        for (int i = 0; i < 8; i++) {
          acc1[i].x = fmaf(w.x, va[i+kx], acc1[i].x);
          acc1[i].y = fmaf(w.y, vb[i+kx], acc1[i].y);
        }
      }
    }
  }
  size_t r0 = (size_t)(b*112+y0)*112 + x0;
  #pragma unroll
  for (int i = 0; i < 8; i++) {
    unsigned o0 = (unsigned)f2b(acc0[i].x) | ((unsigned)f2b(acc0[i].y) << 16);
    unsigned o1 = (unsigned)f2b(acc1[i].x) | ((unsigned)f2b(acc1[i].y) << 16);
    *(unsigned*)(out + (r0+i)*128 + c)       = o0;
    *(unsigned*)(out + (r0+112+i)*128 + c)   = o1;
  }
}

// ---------------- co/di fused dwconv, channel-paired, 2 output rows/thread ----------------
__global__ __launch_bounds__(256) void dwconv_codi_kernel(
    const bf16_t* __restrict__ rgb, const bf16_t* __restrict__ tb,
    const float* __restrict__ w1, const float* __restrict__ b1,
    const float* __restrict__ w2, const float* __restrict__ b2,
    bf16_t* __restrict__ out){
  __shared__ float wsm[49*128];   // [k][co 64 | di 64]
  int t = threadIdx.x;
  // conflict-free staging (consecutive channels -> consecutive banks)
  for (int i = t; i < 3136; i += 256) {
    int ch = i & 63, k = i >> 6;
    wsm[k*128 + ch]      = w1[ch*49 + k];
    wsm[k*128 + 64 + ch] = w2[ch*49 + k];
  }
  __syncthreads();
  int c = (t & 31) * 2;               // channel pair (of 64)
  int wv = t >> 5;                    // 0..7 -> y pair
  int blk = blockIdx.x;               // 8 * 7 * 14
  int xs = blk % 14; int tmp = blk / 14;
  int yg = tmp % 7; int b = tmp / 7;
  int y0 = yg*16 + wv*2;              // outputs y0, y0+1
  int x0 = xs*8;
  float2 bco; bco.x = b1[c]; bco.y = b1[c+1];
  float2 bdi; bdi.x = b2[c]; bdi.y = b2[c+1];
  float2 aco0[8], aco1[8], adi0[8], adi1[8];
  #pragma unroll
  for (int i = 0; i < 8; i++) { aco0[i] = bco; aco1[i] = bco; adi0[i] = bdi; adi1[i] = bdi; }
  for (int r = 0; r < 8; r++) {
    int yy = y0 + r - 3;
    if ((unsigned)yy >= 112u) continue;          // half-wave divergent at edges only
    const bf16_t* rrow = rgb + ((size_t)(b*112+yy)*112)*64 + c;
    const bf16_t* trow = tb  + ((size_t)(b*112+yy)*112)*64 + c;
    unsigned ru[14], tu[14];
    #pragma unroll
    for (int i = 0; i < 14; i++) {
      int xx = x0 + i - 3;
      bool ok = (unsigned)xx < 112u;
      ru[i] = ok ? *(const unsigned*)(rrow + (size_t)xx*64) : 0u;
      tu[i] = ok ? *(const unsigned*)(trow + (size_t)xx*64) : 0u;
    }
    float p0[14], p1[14], d0[14], d1[14];
    #pragma unroll
    for (int i = 0; i < 14; i++) {
      float a0 = blo(ru[i]), a1 = bhi(ru[i]);
      float t0 = blo(tu[i]), t1 = bhi(tu[i]);
      p0[i] = a0*t0; p1[i] = a1*t1;
      d0[i] = fabsf(a0-t0); d1[i] = fabsf(a1-t1);
    }
    if (r < 7) {                                  // yout = y0, ky = r
      #pragma unroll
      for (int kx = 0; kx < 7; kx++) {
        int k = r*7+kx;
        float2 wc = *(const float2*)&wsm[k*128 + c];
        float2 wd = *(const float2*)&wsm[k*128 + 64 + c];
        #pragma unroll
        for (int i = 0; i < 8; i++) {
          aco0[i].x = fmaf(wc.x, p0[i+kx], aco0[i].x);
          aco0[i].y = fmaf(wc.y, p1[i+kx], aco0[i].y);
          adi0[i].x = fmaf(wd.x, d0[i+kx], adi0[i].x);
          adi0[i].y = fmaf(wd.y, d1[i+kx], adi0[i].y);
        }
      }
    }
    if (r >= 1) {                                 // yout = y0+1, ky = r-1
      #pragma unroll
      for (int kx = 0; kx < 7; kx++) {
        int k = (r-1)*7+kx;
        float2 wc = *(const float2*)&wsm[k*128 + c];
        float2 wd = *(const float2*)&wsm[k*128 + 64 + c];
        #pragma unroll
        for (int i = 0; i < 8; i++) {
          aco1[i].x = fmaf(wc.x, p0[i+kx], aco1[i].x);
          aco1[i].y = fmaf(wc.y, p1[i+kx], aco1[i].y);
          adi1[i].x = fmaf(wd.x, d0[i+kx], adi1[i].x);
          adi1[i].y = fmaf(wd.y, d1[i+kx], adi1[i].y);
        }
      }
    }
  }
  size_t r0 = (size_t)(b*112+y0)*112 + x0;
  #pragma unroll
  for (int i = 0; i < 8; i++) {
    unsigned oc0 = (unsigned)f2b(aco0[i].x) | ((unsigned)f2b(aco0[i].y) << 16);
    unsigned od0 = (unsigned)f2b(adi0[i].x) | ((unsigned)f2b(adi0[i].y) << 16);
    unsigned oc1 = (unsigned)f2b(aco1[i].x) | ((unsigned)f2b(aco1[i].y) << 16);
    unsigned od1 = (unsigned)f2b(adi1[i].x) | ((unsigned)f2b(adi1[i].y) << 16);
    *(unsigned*)(out + (r0+i)*128 + c)            = oc0;
    *(unsigned*)(out + (r0+i)*128 + 64 + c)       = od0;
    *(unsigned*)(out + (r0+112+i)*128 + c)        = oc1;
    *(unsigned*)(out + (r0+112+i)*128 + 64 + c)   = od1;
  }
}

// ---------------- cosine-gate reductions (codi bf16) ----------------
__global__ __launch_bounds__(256) void reduce_kernel(const bf16_t* __restrict__ codi,
    float* __restrict__ dotb, float* __restrict__ n1sq, float* __restrict__ n2sq){
  int blk = blockIdx.x;          // 392
  int b = blk / 49, seg = blk % 49;
  int lane = threadIdx.x & 63, w = threadIdx.x >> 6;
  int c = lane*2;
  float d0=0,d1=0,s0=0,s1=0,a1=0;
  for (int i = 0; i < 64; i++) {
    int row = b*HW + seg*256 + w*64 + i;
    ushort2 v2 = *(const ushort2*)(codi + (size_t)row*128 + c);
    float vx = b2f(v2.x), vy = b2f(v2.y);
    float rs = vx + vy;
    #pragma unroll
    for (int o = 1; o < 64; o <<= 1) rs += __shfl_xor(rs, o);
    float amap = rs * (1.0f/128.0f);
    d0 += amap*vx; d1 += amap*vy;
    s0 += vx*vx;   s1 += vy*vy;
    if (lane == 0) a1 += amap*amap;
  }
  atomicAdd(&dotb[b*128+c],   d0); atomicAdd(&dotb[b*128+c+1], d1);
  atomicAdd(&n2sq[b*128+c],   s0); atomicAdd(&n2sq[b*128+c+1], s1);
  if (lane == 0) atomicAdd(&n1sq[b], a1);
}

__global__ __launch_bounds__(128) void attc_kernel(const float* __restrict__ dotb,
    const float* __restrict__ n1sq, const float* __restrict__ n2sq,
    const float* __restrict__ fc1, const float* __restrict__ fc2, float* __restrict__ attc){
  __shared__ float scos[128];
  __shared__ float sh[16];
  int t = threadIdx.x;
  int b = blockIdx.x;
  {
    float n1 = sqrtf(n1sq[b]);
    float n2 = sqrtf(n2sq[b*128+t]);
    scos[t] = dotb[b*128+t] / (n1*n2 + 1e-6f);
  }
  __syncthreads();
  if (t < 16) {
    float h = 0;
    for (int c = 0; c < 128; c++) h += scos[c]*fc1[c*16+t];
    sh[t] = h * 0.5f * (1.0f + erff(h*0.70710678118654752f));
  }
  __syncthreads();
  {
    float a = 0;
    for (int j = 0; j < 16; j++) a += sh[j]*fc2[j*128+t];
    attc[b*128+t] = 1.0f/(1.0f + __expf(-a));
  }
}

// ---------------- pooling (16x16 mean) of [xn|xen] (bf16) ----------------
__global__ void pool_kernel(const bf16_t* __restrict__ xn, const bf16_t* __restrict__ xen,
                            float* __restrict__ pool){
  int cellb = blockIdx.x;
  int py = blockIdx.y;
  int c = threadIdx.x;           // 0..191
  int b = cellb / 49, cell = cellb % 49;
  int wy = cell / 7, wx = cell % 7;
  float s = 0;
  for (int i = py*2; i < py*2+2; i++)
    for (int j = 0; j < 16; j++) {
      int y = wy*16+i, x = wx*16+j;
      size_t row = (size_t)(b*112+y)*112 + x;
      s += (c < 128) ? b2f(xn[row*128 + c]) : b2f(xen[row*64 + (c-128)]);
    }
  atomicAdd(&pool[(size_t)cellb*192 + c], s);
}

// ---------------- q projection ----------------
__global__ void qproj_kernel(const float* __restrict__ pool, const float* __restrict__ qw,
                             const float* __restrict__ qb, float* __restrict__ qbuf){
  int cellb = blockIdx.x;
  int j = threadIdx.x;
  float s = qb[j];
  for (int c = 0; c < 192; c++)
    s += pool[(size_t)cellb*192 + c] * (1.0f/256.0f) * qw[c*64 + j];
  qbuf[(size_t)cellb*64 + j] = s * 0.35355339059327373f;
}

// ---------------- flash attention split-K 28 (kv bf16) ----------------
// 28 splits -> 1792 blocks = 7 blocks/CU resident (LDS 18KB x 7 = 126KB ok):
// raises occupancy 18% -> ~50% to hide the online-softmax dependent chain +
// staging latency. Per-split 448 keys = chunks {256, 192}; per-wave counts
// stay multiples of 16.
__global__ __launch_bounds__(256) void attn_kernel(const float* __restrict__ qbuf,
    const bf16_t* __restrict__ kv, float* __restrict__ part){
  __shared__ float qs[392];
  __shared__ float ks[256*8];
  __shared__ float vs[256*8];
  int t = threadIdx.x;
  int blk = blockIdx.x;          // 1792 = b(8) * nh(8) * sp(28)
  int b = blk / 224, nh = (blk / 28) & 7, sp = blk % 28;
  for (int i = t; i < 392; i += 256)
    qs[i] = qbuf[(size_t)(b*49 + (i>>3))*64 + nh*8 + (i&7)];
  __syncthreads();
  int lane = t & 63, w = t >> 6;
  int qq = lane < 49 ? lane : 0;
  float4 qa = *(const float4*)&qs[qq*8];
  float4 qb4 = *(const float4*)&qs[qq*8+4];
  float m = -1e30f, l = 0.f;
  float4 acca = make_float4(0,0,0,0), accb = make_float4(0,0,0,0);
  const int base = sp * 448;
  uint4 kr, vr;
  {  // prefetch chunk 0 (all 256 threads valid: base+t <= 27*448+255 < 12544)
    size_t rb = ((size_t)(b*HW + base + t))*128 + nh*8;
    kr = *(const uint4*)(kv + rb);
    vr = *(const uint4*)(kv + rb + 64);
  }
  for (int c0 = 0; c0 < 448; c0 += 256) {
    int cnt = 448 - c0 < 256 ? 448 - c0 : 256;
    __syncthreads();
    if (t < cnt) {
      const bf16_t* kp = (const bf16_t*)&kr;
      const bf16_t* vp = (const bf16_t*)&vr;
      float4 k0 = make_float4(b2f(kp[0]), b2f(kp[1]), b2f(kp[2]), b2f(kp[3]));
      float4 k1 = make_float4(b2f(kp[4]), b2f(kp[5]), b2f(kp[6]), b2f(kp[7]));
      float4 v0 = make_float4(b2f(vp[0]), b2f(vp[1]), b2f(vp[2]), b2f(vp[3]));
      float4 v1 = make_float4(b2f(vp[4]), b2f(vp[5]), b2f(vp[6]), b2f(vp[7]));
      *(float4*)&ks[t*8]   = k0; *(float4*)&ks[t*8+4] = k1;
      *(float4*)&vs[t*8]   = v0; *(float4*)&vs[t*8+4] = v1;
    }
    __syncthreads();
    // prefetch next chunk (loads in flight across the compute below)
    int c1 = c0 + 256;
    if (c1 < 448) {
      int cnt1 = 448 - c1 < 256 ? 448 - c1 : 256;
      if (t < cnt1) {
        size_t rb = ((size_t)(b*HW + base + c1 + t))*128 + nh*8;
        kr = *(const uint4*)(kv + rb);
        vr = *(const uint4*)(kv + rb + 64);
      }
    }
    int s0 = w*64;
    int n = cnt - s0; if (n < 0) n = 0; if (n > 64) n = 64;
    // n is always 0 or 64 here (448 = 256 + 192) -> multiple of 16
    for (int i = 0; i < n; i += 16) {
      float s[16];
      #pragma unroll
      for (int j = 0; j < 16; j++) {
        const float* kp = &ks[(s0+i+j)*8];
        float4 ka = *(const float4*)kp, kb = *(const float4*)(kp+4);
        s[j] = qa.x*ka.x + qa.y*ka.y + qa.z*ka.z + qa.w*ka.w
             + qb4.x*kb.x + qb4.y*kb.y + qb4.z*kb.z + qb4.w*kb.w;
      }
      float t8[8];
      #pragma unroll
      for (int j = 0; j < 8; j++) t8[j] = fmaxf(s[2*j], s[2*j+1]);
      float t4a = fmaxf(t8[0], t8[1]), t4b = fmaxf(t8[2], t8[3]);
      float t4c = fmaxf(t8[4], t8[5]), t4d = fmaxf(t8[6], t8[7]);
      float mx = fmaxf(fmaxf(t4a, t4b), fmaxf(t4c, t4d));
      float mn = fmaxf(m, mx);
      float corr = __expf(m - mn);
      float p[16];
      #pragma unroll
      for (int j = 0; j < 16; j++) p[j] = __expf(s[j] - mn);
      float u8[8];
      #pragma unroll
      for (int j = 0; j < 8; j++) u8[j] = p[2*j] + p[2*j+1];
      float u4a = u8[0]+u8[1], u4b = u8[2]+u8[3], u4c = u8[4]+u8[5], u4d = u8[6]+u8[7];
      float lsum = (u4a+u4b) + (u4c+u4d);
      l = fmaf(l, corr, lsum);
      float4 sva = make_float4(0,0,0,0), svb = make_float4(0,0,0,0);
      #pragma unroll
      for (int j = 0; j < 16; j++) {
        const float* vp = &vs[(s0+i+j)*8];
        float4 va = *(const float4*)vp, vb = *(const float4*)(vp+4);
        sva.x = fmaf(p[j], va.x, sva.x); sva.y = fmaf(p[j], va.y, sva.y);
        sva.z = fmaf(p[j], va.z, sva.z); sva.w = fmaf(p[j], va.w, sva.w);
        svb.x = fmaf(p[j], vb.x, svb.x); svb.y = fmaf(p[j], vb.y, svb.y);
        svb.z = fmaf(p[j], vb.z, svb.z); svb.w = fmaf(p[j], vb.w, svb.w);
      }
      acca.x = fmaf(acca.x, corr, sva.x); acca.y = fmaf(acca.y, corr, sva.y);
      acca.z = fmaf(acca.z, corr, sva.z); acca.w = fmaf(acca.w, corr, sva.w);
      accb.x = fmaf(accb.x, corr, svb.x); accb.y = fmaf(accb.y, corr, svb.y);
      accb.z = fmaf(accb.z, corr, svb.z); accb.w = fmaf(accb.w, corr, svb.w);
      m = mn;
    }
  }
  // in-block merge of the 4 wave partials (reuse vs as scratch)
  __syncthreads();
  if (lane < 49) {
    float* rp = &vs[((size_t)w*49 + lane)*10];
    rp[0] = m; rp[1] = l;
    rp[2] = acca.x; rp[3] = acca.y; rp[4] = acca.z; rp[5] = acca.w;
    rp[6] = accb.x; rp[7] = accb.y; rp[8] = accb.z; rp[9] = accb.w;
  }
  __syncthreads();
  if (t < 49) {
    float M = -1e30f;
    #pragma unroll
    for (int w4 = 0; w4 < 4; w4++) M = fmaxf(M, vs[(w4*49 + t)*10]);
    float L = 0, a[8] = {0,0,0,0,0,0,0,0};
    #pragma unroll
    for (int w4 = 0; w4 < 4; w4++) {
      const float* rp = &vs[(w4*49 + t)*10];
      float c = __expf(rp[0] - M);
      L += rp[1]*c;
      #pragma unroll
      for (int d = 0; d < 8; d++) a[d] += rp[2+d]*c;
    }
    size_t idx = ((size_t)blk*49 + t)*10;
    part[idx] = M; part[idx+1] = L;
    #pragma unroll
    for (int d = 0; d < 8; d++) part[idx+2+d] = a[d];
  }
}

__global__ void merge_kernel(const float* __restrict__ part, float* __restrict__ gsm){
  int g = blockIdx.x*64 + threadIdx.x;   // 3136
  if (g >= 3136) return;
  int b = g / 392, r = g % 392, nh = r / 49, q = r % 49;
  int blkbase = b*224 + nh*28;
  float M = -1e30f;
  for (int sp = 0; sp < 28; sp++)
    M = fmaxf(M, part[((size_t)(blkbase+sp)*49 + q)*10]);
  float L = 0, a[8] = {0,0,0,0,0,0,0,0};
  for (int sp = 0; sp < 28; sp++) {
    size_t idx = ((size_t)(blkbase+sp)*49 + q)*10;
    float c = __expf(part[idx] - M);
    L += part[idx+1]*c;
    #pragma unroll
    for (int d = 0; d < 8; d++) a[d] += part[idx+2+d]*c;
  }
  #pragma unroll
  for (int d = 0; d < 8; d++)
    gsm[(size_t)(b*49+q)*64 + nh*8 + d] = a[d]/L;
}

// ---------------- xc cols 128..191: bilinear(g) -> bf16 ----------------
__global__ __launch_bounds__(256) void f2_kernel(const float* __restrict__ gsm,
                                                 bf16_t* __restrict__ xc){
  int gidx = blockIdx.x*256 + threadIdx.x;   // N*64 total
  int r = gidx >> 6, cc = gidx & 63;
  int b = r / HW, rem = r % HW, y = rem / 112, x = rem % 112;
  float fy = fminf(fmaxf((y + 0.5f)*0.0625f - 0.5f, 0.f), 6.f);
  float fx = fminf(fmaxf((x + 0.5f)*0.0625f - 0.5f, 0.f), 6.f);
  int y0 = (int)fy, x0 = (int)fx;
  float wy = fy - y0, wx = fx - x0;
  int y1 = y0+1 < 6 ? y0+1 : 6, x1 = x0+1 < 6 ? x0+1 : 6;
  const float* gb = gsm + (size_t)b*49*64 + cc;
  float g00 = gb[(y0*7+x0)*64], g01 = gb[(y0*7+x1)*64];
  float g10 = gb[(y1*7+x0)*64], g11 = gb[(y1*7+x1)*64];
  xc[(size_t)r*256 + 128 + cc] =
      f2b((1-wy)*((1-wx)*g00 + wx*g01) + wy*((1-wx)*g10 + wx*g11));
}

// =====================================================================
extern "C" void kernel_launch(void* const* d_in, const int* in_sizes, int n_in,
                              void* d_out, int out_size, void* d_ws, size_t ws_size,
                              hipStream_t stream) {
  const float* x      = (const float*)d_in[0];
  const float* x_e    = (const float*)d_in[1];
  const float* norm_w = (const float*)d_in[2];
  const float* norm_b = (const float*)d_in[3];
  const float* norme_w= (const float*)d_in[4];
  const float* norme_b= (const float*)d_in[5];
  const float* rr1_w  = (const float*)d_in[6];
  const float* rr1_b  = (const float*)d_in[7];
  const float* rr2_w  = (const float*)d_in[8];
  const float* rr2_b  = (const float*)d_in[9];
  const float* rr3_w  = (const float*)d_in[10];
  const float* rr3_b  = (const float*)d_in[11];
  const float* conv_w = (const float*)d_in[12];
  const float* conv_b = (const float*)d_in[13];
  const float* la1_w  = (const float*)d_in[14];
  const float* la1_b  = (const float*)d_in[15];
  const float* la2_w  = (const float*)d_in[16];
  const float* la2_b  = (const float*)d_in[17];
  const float* lac1_w = (const float*)d_in[18];
  const float* lac1_b = (const float*)d_in[19];
  const float* lac2_w = (const float*)d_in[20];
  const float* lac2_b = (const float*)d_in[21];
  const float* fc1_w  = (const float*)d_in[22];
  const float* fc2_w  = (const float*)d_in[23];
  const float* la3_w  = (const float*)d_in[24];
  const float* la3_b  = (const float*)d_in[25];
  const float* kv_w   = (const float*)d_in[26];
  const float* kv_b   = (const float*)d_in[27];
  const float* q_w    = (const float*)d_in[28];
  const float* q_b    = (const float*)d_in[29];
  const float* proj_w = (const float*)d_in[30];
  const float* proj_b = (const float*)d_in[31];
  const float* proje_w= (const float*)d_in[32];
  const float* proje_b= (const float*)d_in[33];

  const size_t N = N_POS;
  bf16_t* rr1   = (bf16_t*)d_ws;     // N*128 bf16, dead after G3
  bf16_t* xnbuf = rr1 + N*128;       // N*128: xn -> convout
  bf16_t* kvbuf = xnbuf + N*128;     // N*128: kv -> codi
  bf16_t* xcbuf = kvbuf + N*128;     // N*256: [rr2a | rgb | xen/t] -> xc
  float* pool = (float*)(xcbuf + N*256);  // 75264
  float* qbuf = pool + 75264;        // 25088
  float* part = qbuf + 25088;        // 1003520 (uses 878080)
  float* gsm  = part + 1003520;      // 25088
  float* dotb = gsm  + 25088;        // 1024
  float* n1sq = dotb + 1024;         // 8
  float* n2sq = n1sq + 8;            // 1024
  float* attc = n2sq + 1024;         // 1024
  bf16_t* wtab = (bf16_t*)(attc + 1024);  // 135168 shorts

  bf16_t* xn = xnbuf;
  bf16_t* convout = xnbuf;
  bf16_t* kv = kvbuf;
  bf16_t* codi = kvbuf;
  bf16_t* rr2a = xcbuf;
  bf16_t* rgb  = xcbuf + N*128;
  bf16_t* xen  = xcbuf + N*192;
  bf16_t* xc   = xcbuf;
  float* outp = (float*)d_out;
  float* oute = outp + N*128;

  bf16_t* rr1t0 = wtab;            bf16_t* rr1t1 = wtab + 8192;
  bf16_t* rr2t0 = wtab + 16384;    bf16_t* rr2t1 = wtab + 24576;
  bf16_t* la1t  = wtab + 32768;
  bf16_t* kvt0  = wtab + 40960;    bf16_t* kvt1  = wtab + 49152;
  bf16_t* la2t  = wtab + 57344;
  bf16_t* rr3t0 = wtab + 61440;    bf16_t* rr3t1 = wtab + 69632;
  bf16_t* la3t  = wtab + 77824;
  bf16_t* projt0= wtab + 86016;    bf16_t* projt1= wtab + 102400;
  bf16_t* projet= wtab + 118784;

  zero_kernel<<<(75264+255)/256, 256, 0, stream>>>(pool, 75264);
  zero_kernel<<<9, 256, 0, stream>>>(dotb, 2056);
  {
    WJobs js;
    js.j[0]  = {rr1_w,  rr1t0, 128, 128,   0};
    js.j[1]  = {rr1_w,  rr1t1, 128, 128,  64};
    js.j[2]  = {rr2_w,  rr2t0, 128, 128,   0};
    js.j[3]  = {rr2_w,  rr2t1, 128, 128,  64};
    js.j[4]  = {la1_w,  la1t,  128,  64,   0};
    js.j[5]  = {kv_w,   kvt0,  128, 128,   0};
    js.j[6]  = {kv_w,   kvt1,  128, 128,  64};
    js.j[7]  = {la2_w,  la2t,   64,  64,   0};
    js.j[8]  = {rr3_w,  rr3t0, 128, 128,   0};
    js.j[9]  = {rr3_w,  rr3t1, 128, 128,  64};
    js.j[10] = {la3_w,  la3t,  128,  64,   0};
    js.j[11] = {proj_w, projt0,256, 128,   0};
    js.j[12] = {proj_w, projt1,256, 128,  64};
    js.j[13] = {proje_w,projet,256,  64,   0};
    wtrans_kernel<<<14, 256, 0, stream>>>(js);
  }
  ln128_kernel<<<N_POS/4, 256, 0, stream>>>(x, norm_w, norm_b, xn);
  ln64_kernel <<<N_POS/4, 256, 0, stream>>>(x_e, norme_w, norme_b, xen);
  pool_kernel<<<dim3(392,8), 192, 0, stream>>>(xn, xen, pool);
  qproj_kernel<<<392, 64, 0, stream>>>(pool, q_w, q_b, qbuf);
  // G1: xn -> rr1 | rr2a | rgb | kv   (7 tiles, XCD-local)
  {
    MGemmParams p; p.A = xn; p.scale = 0; p.lda = 128; p.K = 128; p.rowsPerB = HW; p.ntiles = 7;
    p.tiles[0] = {rr1t0, rr1_b,    rr1,     0, 128, 0, 0};
    p.tiles[1] = {rr1t1, rr1_b+64, rr1+64,  0, 128, 0, 0};
    p.tiles[2] = {rr2t0, rr2_b,    rr2a,    0, 128, 0, 0};
    p.tiles[3] = {rr2t1, rr2_b+64, rr2a+64, 0, 128, 0, 0};
    p.tiles[4] = {la1t,  la1_b,    rgb,     0,  64, 0, 0};
    p.tiles[5] = {kvt0,  kv_b,     kv,      0, 128, 0, 0};
    p.tiles[6] = {kvt1,  kv_b+64,  kv+64,   0, 128, 0, 0};
    mgemm<<<8*7*98, 256, 0, stream>>>(p);
  }
  attn_kernel<<<1792, 256, 0, stream>>>(qbuf, kv, part);
  merge_kernel<<<49, 64, 0, stream>>>(part, gsm);
  // G2: xen -> t (in-place)
  {
    MGemmParams p; p.A = xen; p.scale = 0; p.lda = 64; p.K = 64; p.rowsPerB = HW; p.ntiles = 1;
    p.tiles[0] = {la2t, la2_b, xen, 0, 64, 0, 0};
    mgemm<<<8*1*98, 256, 0, stream>>>(p);
  }
  dwconv_codi_kernel<<<8*7*14, 256, 0, stream>>>(rgb, xen, lac1_w, lac1_b, lac2_w, lac2_b, codi);
  dwconv128_kernel<<<8*14*14, 256, 0, stream>>>(rr2a, conv_w, conv_b, convout);
  // G3: (convout@rr3 + b) * rr1 -> xc cols 0..127
  {
    MGemmParams p; p.A = convout; p.scale = 0; p.lda = 128; p.K = 128; p.rowsPerB = HW; p.ntiles = 2;
    p.tiles[0] = {rr3t0, rr3_b,    xc,    rr1,    256, 128, 0};
    p.tiles[1] = {rr3t1, rr3_b+64, xc+64, rr1+64, 256, 128, 0};
    mgemm<<<8*2*98, 256, 0, stream>>>(p);
  }
  reduce_kernel<<<392, 256, 0, stream>>>(codi, dotb, n1sq, n2sq);
  attc_kernel<<<8, 128, 0, stream>>>(dotb, n1sq, n2sq, fc1_w, fc2_w, attc);
  // G4: (codi * attc) @ la3 -> xc cols 192..255
  {
    MGemmParams p; p.A = codi; p.scale = attc; p.lda = 128; p.K = 128; p.rowsPerB = HW; p.ntiles = 1;
    p.tiles[0] = {la3t, la3_b, xc + 192, 0, 256, 0, 0};
    mgemm<<<8*1*98, 256, 0, stream>>>(p);
  }
  f2_kernel<<<25088, 256, 0, stream>>>(gsm, xc);
  // G5: xc -> out | out_e (fp32 outputs)
  {
    MGemmParams p; p.A = xc; p.scale = 0; p.lda = 256; p.K = 256; p.rowsPerB = HW; p.ntiles = 3;
    p.tiles[0] = {projt0, proj_b,    outp,    0, 128, 0, 1};
    p.tiles[1] = {projt1, proj_b+64, outp+64, 0, 128, 0, 1};
    p.tiles[2] = {projet, proje_b,   oute,    0,  64, 0, 1};
    mgemm<<<8*3*98, 256, 0, stream>>>(p);
  }
}

// Round 10
// 575.818 us; speedup vs baseline: 1.1913x; 1.0363x over previous
//
#include <hip/hip_runtime.h>
#include <math.h>

#define N_POS 100352   // 8*112*112
#define HW    12544    // 112*112

typedef unsigned short bf16_t;
typedef __attribute__((ext_vector_type(8))) short bf16x8;
typedef __attribute__((ext_vector_type(4))) float f32x4;

__device__ __forceinline__ bf16_t f2b(float f){
  unsigned u = __builtin_bit_cast(unsigned, f);
  unsigned r = (u + 0x7fffu + ((u >> 16) & 1u)) >> 16;
  return (bf16_t)r;
}
__device__ __forceinline__ float b2f(bf16_t h){
  unsigned u = ((unsigned)h) << 16;
  return __builtin_bit_cast(float, u);
}
__device__ __forceinline__ float blo(unsigned u){
  return __builtin_bit_cast(float, u << 16);
}
__device__ __forceinline__ float bhi(unsigned u){
  return __builtin_bit_cast(float, u & 0xffff0000u);
}
// async global->LDS, 16B per lane; LDS dest is wave-uniform base + lane*16
__device__ __forceinline__ void gload16(const void* g, void* l){
  __builtin_amdgcn_global_load_lds(
      (const __attribute__((address_space(1))) unsigned*)g,
      (__attribute__((address_space(3))) unsigned*)l, 16, 0, 0);
}

// ---------------- zero ----------------
__global__ void zero_kernel(float* p, int n){
  int i = blockIdx.x*256 + threadIdx.x;
  if (i < n) p[i] = 0.f;
}

// ---------------- weight transpose+cast: Wt[n][k] = bf16(W[k][n0+n]) ----------------
struct WJob { const float* src; bf16_t* dst; int K; int ldw; int n0; };
struct WJobs { WJob j[14]; };
__global__ void wtrans_kernel(WJobs js){
  WJob job = js.j[blockIdx.x];
  int t = threadIdx.x;
  int n = t & 63, k0 = t >> 6;
  for (int k = k0; k < job.K; k += 4)
    job.dst[(size_t)n*job.K + k] = f2b(job.src[(size_t)k*job.ldw + job.n0 + n]);
}

// ---------------- LayerNorm (128 ch) -> bf16 ----------------
__global__ __launch_bounds__(256) void ln128_kernel(const float* __restrict__ in,
    const float* __restrict__ w, const float* __restrict__ b, bf16_t* __restrict__ out){
  int row  = blockIdx.x*4 + (threadIdx.x >> 6);
  int lane = threadIdx.x & 63;
  const float* p = in + (size_t)row*128;
  float2 v = *(const float2*)(p + lane*2);
  float s = v.x + v.y;
  #pragma unroll
  for (int o = 1; o < 64; o <<= 1) s += __shfl_xor(s, o);
  float mu = s * (1.0f/128.0f);
  float dx = v.x - mu, dy = v.y - mu;
  float q = dx*dx + dy*dy;
  #pragma unroll
  for (int o = 1; o < 64; o <<= 1) q += __shfl_xor(q, o);
  float rs = rsqrtf(q * (1.0f/128.0f) + 1e-6f);
  int c = lane*2;
  ushort2 o2;
  o2.x = f2b(dx*rs*w[c]   + b[c]);
  o2.y = f2b(dy*rs*w[c+1] + b[c+1]);
  *(ushort2*)(out + (size_t)row*128 + c) = o2;
}

// ---------------- LayerNorm (64 ch) -> bf16 ----------------
__global__ __launch_bounds__(256) void ln64_kernel(const float* __restrict__ in,
    const float* __restrict__ w, const float* __restrict__ b, bf16_t* __restrict__ out){
  int row  = blockIdx.x*4 + (threadIdx.x >> 6);
  int lane = threadIdx.x & 63;
  float v = in[(size_t)row*64 + lane];
  float s = v;
  #pragma unroll
  for (int o = 1; o < 64; o <<= 1) s += __shfl_xor(s, o);
  float mu = s * (1.0f/64.0f);
  float d = v - mu;
  float q = d*d;
  #pragma unroll
  for (int o = 1; o < 64; o <<= 1) q += __shfl_xor(q, o);
  float rs = rsqrtf(q * (1.0f/64.0f) + 1e-6f);
  out[(size_t)row*64 + lane] = f2b(d*rs*w[lane] + b[lane]);
}

// ---------------- bf16 MFMA GEMM: 128x64 block, 4 waves x (32x64) ----------------
// Round-3 proven schedule (FROZEN grid/barriers/epilogue) + global_load_lds
// staging: linear LDS [128][64], inverse-XOR-swizzled global source, swizzled
// fragment reads (chunk ^ (row&7)) -> bank-uniform, no VGPR round trip, no
// ds_write. Scale path (G4) keeps register staging in the same layout.
struct MTile {
  const bf16_t* Wt;    // [64][K] pre-transposed bf16
  const float* bias;
  void* out;           // bf16 or fp32 (out_fp32)
  const bf16_t* mult;  // optional gate, bf16 [row][ldm]
  int ldo; int ldm; int out_fp32;
};
struct MGemmParams {
  const bf16_t* A; const float* scale;
  int lda; int K; int rowsPerB; int ntiles;
  MTile tiles[8];
};

__global__ __launch_bounds__(256) void mgemm(MGemmParams p){
  __shared__ __align__(16) short As[128*64];
  __shared__ __align__(16) short Ws[64*64];
  const int tid = threadIdx.x;
  const int bid = blockIdx.x;
  const int xcd = bid & 7;
  const int j = bid >> 3;
  const int ti = j % p.ntiles;
  const int rb = (j / p.ntiles) * 8 + xcd;      // 0..783 (784 % 8 == 0)
  const MTile tile = p.tiles[ti];
  const int row0 = rb * 128;
  const int lane = tid & 63, wv = tid >> 6;
  const int wm = wv * 32;
  const int fm = lane & 15;
  const int quad = lane >> 4;
  const int lw = lane >> 3, lc = lane & 7;   // row-within-8, chunk
  const int cs = lc ^ lw;                    // inverse-swizzled source chunk
  f32x4 acc[2][4];
  #pragma unroll
  for (int mi = 0; mi < 2; mi++)
    #pragma unroll
    for (int ni = 0; ni < 4; ni++) acc[mi][ni] = (f32x4)0.f;
  const float* scale = p.scale ? (p.scale + (size_t)(row0 / p.rowsPerB) * p.K) : (const float*)0;

  const int sr = tid & 127, sq = tid >> 7;

  for (int k0 = 0; k0 < p.K; k0 += 64) {
    if (!scale) {
      // A: wave wv stages rows wv*32..wv*32+31, 4 calls x 1KB
      const bf16_t* ga = p.A + (size_t)(row0 + wv*32 + lw)*p.lda + k0 + cs*8;
      #pragma unroll
      for (int i = 0; i < 4; i++)
        gload16(ga + (size_t)(i*8)*p.lda, &As[wv*2048 + i*512]);
    } else {
      // register staging into the same swizzled layout
      const bf16_t* src = p.A + (size_t)(row0 + sr)*p.lda + k0;
      const float* sc = scale + k0;
      #pragma unroll
      for (int i = 0; i < 4; i++) {
        int c = sq*4 + i;
        short tmp[8];
        #pragma unroll
        for (int j2 = 0; j2 < 8; j2++)
          tmp[j2] = (short)f2b(b2f(src[c*8 + j2]) * sc[c*8 + j2]);
        *(uint4*)&As[sr*64 + (c ^ (sr & 7))*8] = *(const uint4*)tmp;
      }
    }
    {
      // W: wave wv stages rows wv*16..wv*16+15, 2 calls x 1KB
      const bf16_t* gw = tile.Wt + (size_t)(wv*16 + lw)*p.K + k0 + cs*8;
      gload16(gw,                    &Ws[wv*1024]);
      gload16(gw + (size_t)8*p.K,    &Ws[wv*1024 + 512]);
    }
    __syncthreads();   // drains vmcnt (gload_lds) + lgkm
    #pragma unroll
    for (int ks = 0; ks < 2; ks++) {
      int kb8 = ((ks*4 + quad) ^ (fm & 7)) * 8;   // swizzled chunk
      bf16x8 af0 = *(const bf16x8*)&As[(wm + fm)*64 + kb8];
      bf16x8 af1 = *(const bf16x8*)&As[(wm + 16 + fm)*64 + kb8];
      bf16x8 bfr[4];
      #pragma unroll
      for (int ni = 0; ni < 4; ni++) bfr[ni] = *(const bf16x8*)&Ws[(ni*16 + fm)*64 + kb8];
      #pragma unroll
      for (int ni = 0; ni < 4; ni++) {
        acc[0][ni] = __builtin_amdgcn_mfma_f32_16x16x32_bf16(af0, bfr[ni], acc[0][ni], 0, 0, 0);
        acc[1][ni] = __builtin_amdgcn_mfma_f32_16x16x32_bf16(af1, bfr[ni], acc[1][ni], 0, 0, 0);
      }
    }
    __syncthreads();
  }
  #pragma unroll
  for (int mi = 0; mi < 2; mi++) {
    #pragma unroll
    for (int ni = 0; ni < 4; ni++) {
      int col = ni*16 + fm;
      float bias = tile.bias[col];
      #pragma unroll
      for (int r = 0; r < 4; r++) {
        int row = row0 + wm + mi*16 + quad*4 + r;
        float val = acc[mi][ni][r] + bias;
        if (tile.mult) val *= b2f(tile.mult[(size_t)row*tile.ldm + col]);
        if (tile.out_fp32) ((float*)tile.out)[(size_t)row*tile.ldo + col] = val;
        else ((bf16_t*)tile.out)[(size_t)row*tile.ldo + col] = f2b(val);
      }
    }
  }
}

// ---------------- 7x7 depthwise conv, 128 ch ----------------
__global__ __launch_bounds__(256) void dwconv128_kernel(const bf16_t* __restrict__ in,
    const float* __restrict__ cw, const float* __restrict__ cb, bf16_t* __restrict__ out){
  __shared__ float wsm[49*128];
  int t = threadIdx.x;
  // conflict-free staging: wave writes consecutive channels -> consecutive banks
  for (int i = t; i < 6272; i += 256) {
    int ch = i & 127, k = i >> 7;
    wsm[k*128 + ch] = cw[ch*49 + k];
  }
  __syncthreads();
  int c = (t & 63) * 2;               // channel pair base
  int wv = t >> 6;                    // 0..3 -> y pair
  int blk = blockIdx.x;               // 8 * 14 * 14
  int xs = blk % 14; int tmp = blk / 14;
  int yg = tmp % 14; int b = tmp / 14;
  int y0 = yg*8 + wv*2;               // outputs y0, y0+1
  int x0 = xs*8;
  float2 bias; bias.x = cb[c]; bias.y = cb[c+1];
  float2 acc0[8], acc1[8];
  #pragma unroll
  for (int i = 0; i < 8; i++) { acc0[i] = bias; acc1[i] = bias; }
  for (int r = 0; r < 8; r++) {
    int yy = y0 + r - 3;
    if ((unsigned)yy >= 112u) continue;          // wave-uniform
    const bf16_t* row = in + ((size_t)(b*112+yy)*112)*128 + c;
    unsigned u[14];
    #pragma unroll
    for (int i = 0; i < 14; i++) {
      int xx = x0 + i - 3;
      u[i] = ((unsigned)xx < 112u) ? *(const unsigned*)(row + (size_t)xx*128) : 0u;
    }
    float va[14], vb[14];
    #pragma unroll
    for (int i = 0; i < 14; i++) { va[i] = blo(u[i]); vb[i] = bhi(u[i]); }
    if (r < 7) {                                  // yout = y0, ky = r
      #pragma unroll
      for (int kx = 0; kx < 7; kx++) {
        float2 w = *(const float2*)&wsm[(r*7+kx)*128 + c];
        #pragma unroll
        for (int i = 0; i < 8; i++) {
          acc0[i].x = fmaf(w.x, va[i+kx], acc0[i].x);
          acc0[i].y = fmaf(w.y, vb[i+kx], acc0[i].y);
        }
      }
    }
    if (r >= 1) {                                 // yout = y0+1, ky = r-1
      #pragma unroll
      for (int kx = 0; kx < 7; kx++) {
        float2 w = *(const float2*)&wsm[((r-1)*7+kx)*128 + c];
        #pragma unroll
        for (int i = 0; i < 8; i++) {
          acc1[i].x = fmaf(w.x, va[i+kx], acc1[i].x);
          acc1[i].y = fmaf(w.y, vb[i+kx], acc1[i].y);
        }
      }
    }
  }
  size_t r0 = (size_t)(b*112+y0)*112 + x0;
  #pragma unroll
  for (int i = 0; i < 8; i++) {
    unsigned o0 = (unsigned)f2b(acc0[i].x) | ((unsigned)f2b(acc0[i].y) << 16);
    unsigned o1 = (unsigned)f2b(acc1[i].x) | ((unsigned)f2b(acc1[i].y) << 16);
    *(unsigned*)(out + (r0+i)*128 + c)       = o0;
    *(unsigned*)(out + (r0+112+i)*128 + c)   = o1;
  }
}

// ---------------- co/di fused dwconv, channel-paired, 2 output rows/thread ----------------
__global__ __launch_bounds__(256) void dwconv_codi_kernel(
    const bf16_t* __restrict__ rgb, const bf16_t* __restrict__ tb,
    const float* __restrict__ w1, const float* __restrict__ b1,
    const float* __restrict__ w2, const float* __restrict__ b2,
    bf16_t* __restrict__ out){
  __shared__ float wsm[49*128];   // [k][co 64 | di 64]
  int t = threadIdx.x;
  // conflict-free staging (consecutive channels -> consecutive banks)
  for (int i = t; i < 3136; i += 256) {
    int ch = i & 63, k = i >> 6;
    wsm[k*128 + ch]      = w1[ch*49 + k];
    wsm[k*128 + 64 + ch] = w2[ch*49 + k];
  }
  __syncthreads();
  int c = (t & 31) * 2;               // channel pair (of 64)
  int wv = t >> 5;                    // 0..7 -> y pair
  int blk = blockIdx.x;               // 8 * 7 * 14
  int xs = blk % 14; int tmp = blk / 14;
  int yg = tmp % 7; int b = tmp / 7;
  int y0 = yg*16 + wv*2;              // outputs y0, y0+1
  int x0 = xs*8;
  float2 bco; bco.x = b1[c]; bco.y = b1[c+1];
  float2 bdi; bdi.x = b2[c]; bdi.y = b2[c+1];
  float2 aco0[8], aco1[8], adi0[8], adi1[8];
  #pragma unroll
  for (int i = 0; i < 8; i++) { aco0[i] = bco; aco1[i] = bco; adi0[i] = bdi; adi1[i] = bdi; }
  for (int r = 0; r < 8; r++) {
    int yy = y0 + r - 3;
    if ((unsigned)yy >= 112u) continue;          // half-wave divergent at edges only
    const bf16_t* rrow = rgb + ((size_t)(b*112+yy)*112)*64 + c;
    const bf16_t* trow = tb  + ((size_t)(b*112+yy)*112)*64 + c;
    unsigned ru[14], tu[14];
    #pragma unroll
    for (int i = 0; i < 14; i++) {
      int xx = x0 + i - 3;
      bool ok = (unsigned)xx < 112u;
      ru[i] = ok ? *(const unsigned*)(rrow + (size_t)xx*64) : 0u;
      tu[i] = ok ? *(const unsigned*)(trow + (size_t)xx*64) : 0u;
    }
    float p0[14], p1[14], d0[14], d1[14];
    #pragma unroll
    for (int i = 0; i < 14; i++) {
      float a0 = blo(ru[i]), a1 = bhi(ru[i]);
      float t0 = blo(tu[i]), t1 = bhi(tu[i]);
      p0[i] = a0*t0; p1[i] = a1*t1;
      d0[i] = fabsf(a0-t0); d1[i] = fabsf(a1-t1);
    }
    if (r < 7) {                                  // yout = y0, ky = r
      #pragma unroll
      for (int kx = 0; kx < 7; kx++) {
        int k = r*7+kx;
        float2 wc = *(const float2*)&wsm[k*128 + c];
        float2 wd = *(const float2*)&wsm[k*128 + 64 + c];
        #pragma unroll
        for (int i = 0; i < 8; i++) {
          aco0[i].x = fmaf(wc.x, p0[i+kx], aco0[i].x);
          aco0[i].y = fmaf(wc.y, p1[i+kx], aco0[i].y);
          adi0[i].x = fmaf(wd.x, d0[i+kx], adi0[i].x);
          adi0[i].y = fmaf(wd.y, d1[i+kx], adi0[i].y);
        }
      }
    }
    if (r >= 1) {                                 // yout = y0+1, ky = r-1
      #pragma unroll
      for (int kx = 0; kx < 7; kx++) {
        int k = (r-1)*7+kx;
        float2 wc = *(const float2*)&wsm[k*128 + c];
        float2 wd = *(const float2*)&wsm[k*128 + 64 + c];
        #pragma unroll
        for (int i = 0; i < 8; i++) {
          aco1[i].x = fmaf(wc.x, p0[i+kx], aco1[i].x);
          aco1[i].y = fmaf(wc.y, p1[i+kx], aco1[i].y);
          adi1[i].x = fmaf(wd.x, d0[i+kx], adi1[i].x);
          adi1[i].y = fmaf(wd.y, d1[i+kx], adi1[i].y);
        }
      }
    }
  }
  size_t r0 = (size_t)(b*112+y0)*112 + x0;
  #pragma unroll
  for (int i = 0; i < 8; i++) {
    unsigned oc0 = (unsigned)f2b(aco0[i].x) | ((unsigned)f2b(aco0[i].y) << 16);
    unsigned od0 = (unsigned)f2b(adi0[i].x) | ((unsigned)f2b(adi0[i].y) << 16);
    unsigned oc1 = (unsigned)f2b(aco1[i].x) | ((unsigned)f2b(aco1[i].y) << 16);
    unsigned od1 = (unsigned)f2b(adi1[i].x) | ((unsigned)f2b(adi1[i].y) << 16);
    *(unsigned*)(out + (r0+i)*128 + c)            = oc0;
    *(unsigned*)(out + (r0+i)*128 + 64 + c)       = od0;
    *(unsigned*)(out + (r0+112+i)*128 + c)        = oc1;
    *(unsigned*)(out + (r0+112+i)*128 + 64 + c)   = od1;
  }
}

// ---------------- cosine-gate reductions (codi bf16) ----------------
__global__ __launch_bounds__(256) void reduce_kernel(const bf16_t* __restrict__ codi,
    float* __restrict__ dotb, float* __restrict__ n1sq, float* __restrict__ n2sq){
  int blk = blockIdx.x;          // 392
  int b = blk / 49, seg = blk % 49;
  int lane = threadIdx.x & 63, w = threadIdx.x >> 6;
  int c = lane*2;
  float d0=0,d1=0,s0=0,s1=0,a1=0;
  for (int i = 0; i < 64; i++) {
    int row = b*HW + seg*256 + w*64 + i;
    ushort2 v2 = *(const ushort2*)(codi + (size_t)row*128 + c);
    float vx = b2f(v2.x), vy = b2f(v2.y);
    float rs = vx + vy;
    #pragma unroll
    for (int o = 1; o < 64; o <<= 1) rs += __shfl_xor(rs, o);
    float amap = rs * (1.0f/128.0f);
    d0 += amap*vx; d1 += amap*vy;
    s0 += vx*vx;   s1 += vy*vy;
    if (lane == 0) a1 += amap*amap;
  }
  atomicAdd(&dotb[b*128+c],   d0); atomicAdd(&dotb[b*128+c+1], d1);
  atomicAdd(&n2sq[b*128+c],   s0); atomicAdd(&n2sq[b*128+c+1], s1);
  if (lane == 0) atomicAdd(&n1sq[b], a1);
}

__global__ __launch_bounds__(128) void attc_kernel(const float* __restrict__ dotb,
    const float* __restrict__ n1sq, const float* __restrict__ n2sq,
    const float* __restrict__ fc1, const float* __restrict__ fc2, float* __restrict__ attc){
  __shared__ float scos[128];
  __shared__ float sh[16];
  int t = threadIdx.x;
  int b = blockIdx.x;
  {
    float n1 = sqrtf(n1sq[b]);
    float n2 = sqrtf(n2sq[b*128+t]);
    scos[t] = dotb[b*128+t] / (n1*n2 + 1e-6f);
  }
  __syncthreads();
  if (t < 16) {
    float h = 0;
    for (int c = 0; c < 128; c++) h += scos[c]*fc1[c*16+t];
    sh[t] = h * 0.5f * (1.0f + erff(h*0.70710678118654752f));
  }
  __syncthreads();
  {
    float a = 0;
    for (int j = 0; j < 16; j++) a += sh[j]*fc2[j*128+t];
    attc[b*128+t] = 1.0f/(1.0f + __expf(-a));
  }
}

// ---------------- pooling (16x16 mean) of [xn|xen] (bf16) ----------------
__global__ void pool_kernel(const bf16_t* __restrict__ xn, const bf16_t* __restrict__ xen,
                            float* __restrict__ pool){
  int cellb = blockIdx.x;
  int py = blockIdx.y;
  int c = threadIdx.x;           // 0..191
  int b = cellb / 49, cell = cellb % 49;
  int wy = cell / 7, wx = cell % 7;
  float s = 0;
  for (int i = py*2; i < py*2+2; i++)
    for (int j = 0; j < 16; j++) {
      int y = wy*16+i, x = wx*16+j;
      size_t row = (size_t)(b*112+y)*112 + x;
      s += (c < 128) ? b2f(xn[row*128 + c]) : b2f(xen[row*64 + (c-128)]);
    }
  atomicAdd(&pool[(size_t)cellb*192 + c], s);
}

// ---------------- q projection ----------------
__global__ void qproj_kernel(const float* __restrict__ pool, const float* __restrict__ qw,
                             const float* __restrict__ qb, float* __restrict__ qbuf){
  int cellb = blockIdx.x;
  int j = threadIdx.x;
  float s = qb[j];
  for (int c = 0; c < 192; c++)
    s += pool[(size_t)cellb*192 + c] * (1.0f/256.0f) * qw[c*64 + j];
  qbuf[(size_t)cellb*64 + j] = s * 0.35355339059327373f;
}

// ---------------- flash attention split-K 28 (kv bf16) ----------------
__global__ __launch_bounds__(256) void attn_kernel(const float* __restrict__ qbuf,
    const bf16_t* __restrict__ kv, float* __restrict__ part){
  __shared__ float qs[392];
  __shared__ float ks[256*8];
  __shared__ float vs[256*8];
  int t = threadIdx.x;
  int blk = blockIdx.x;          // 1792 = b(8) * nh(8) * sp(28)
  int b = blk / 224, nh = (blk / 28) & 7, sp = blk % 28;
  for (int i = t; i < 392; i += 256)
    qs[i] = qbuf[(size_t)(b*49 + (i>>3))*64 + nh*8 + (i&7)];
  __syncthreads();
  int lane = t & 63, w = t >> 6;
  int qq = lane < 49 ? lane : 0;
  float4 qa = *(const float4*)&qs[qq*8];
  float4 qb4 = *(const float4*)&qs[qq*8+4];
  float m = -1e30f, l = 0.f;
  float4 acca = make_float4(0,0,0,0), accb = make_float4(0,0,0,0);
  const int base = sp * 448;
  uint4 kr, vr;
  {
    size_t rb = ((size_t)(b*HW + base + t))*128 + nh*8;
    kr = *(const uint4*)(kv + rb);
    vr = *(const uint4*)(kv + rb + 64);
  }
  for (int c0 = 0; c0 < 448; c0 += 256) {
    int cnt = 448 - c0 < 256 ? 448 - c0 : 256;
    __syncthreads();
    if (t < cnt) {
      const bf16_t* kp = (const bf16_t*)&kr;
      const bf16_t* vp = (const bf16_t*)&vr;
      float4 k0 = make_float4(b2f(kp[0]), b2f(kp[1]), b2f(kp[2]), b2f(kp[3]));
      float4 k1 = make_float4(b2f(kp[4]), b2f(kp[5]), b2f(kp[6]), b2f(kp[7]));
      float4 v0 = make_float4(b2f(vp[0]), b2f(vp[1]), b2f(vp[2]), b2f(vp[3]));
      float4 v1 = make_float4(b2f(vp[4]), b2f(vp[5]), b2f(vp[6]), b2f(vp[7]));
      *(float4*)&ks[t*8]   = k0; *(float4*)&ks[t*8+4] = k1;
      *(float4*)&vs[t*8]   = v0; *(float4*)&vs[t*8+4] = v1;
    }
    __syncthreads();
    int c1 = c0 + 256;
    if (c1 < 448) {
      int cnt1 = 448 - c1 < 256 ? 448 - c1 : 256;
      if (t < cnt1) {
        size_t rb = ((size_t)(b*HW + base + c1 + t))*128 + nh*8;
        kr = *(const uint4*)(kv + rb);
        vr = *(const uint4*)(kv + rb + 64);
      }
    }
    int s0 = w*64;
    int n = cnt - s0; if (n < 0) n = 0; if (n > 64) n = 64;
    for (int i = 0; i < n; i += 16) {
      float s[16];
      #pragma unroll
      for (int j = 0; j < 16; j++) {
        const float* kp = &ks[(s0+i+j)*8];
        float4 ka = *(const float4*)kp, kb = *(const float4*)(kp+4);
        s[j] = qa.x*ka.x + qa.y*ka.y + qa.z*ka.z + qa.w*ka.w
             + qb4.x*kb.x + qb4.y*kb.y + qb4.z*kb.z + qb4.w*kb.w;
      }
      float t8[8];
      #pragma unroll
      for (int j = 0; j < 8; j++) t8[j] = fmaxf(s[2*j], s[2*j+1]);
      float t4a = fmaxf(t8[0], t8[1]), t4b = fmaxf(t8[2], t8[3]);
      float t4c = fmaxf(t8[4], t8[5]), t4d = fmaxf(t8[6], t8[7]);
      float mx = fmaxf(fmaxf(t4a, t4b), fmaxf(t4c, t4d));
      float mn = fmaxf(m, mx);
      float corr = __expf(m - mn);
      float p[16];
      #pragma unroll
      for (int j = 0; j < 16; j++) p[j] = __expf(s[j] - mn);
      float u8[8];
      #pragma unroll
      for (int j = 0; j < 8; j++) u8[j] = p[2*j] + p[2*j+1];
      float u4a = u8[0]+u8[1], u4b = u8[2]+u8[3], u4c = u8[4]+u8[5], u4d = u8[6]+u8[7];
      float lsum = (u4a+u4b) + (u4c+u4d);
      l = fmaf(l, corr, lsum);
      float4 sva = make_float4(0,0,0,0), svb = make_float4(0,0,0,0);
      #pragma unroll
      for (int j = 0; j < 16; j++) {
        const float* vp = &vs[(s0+i+j)*8];
        float4 va = *(const float4*)vp, vb = *(const float4*)(vp+4);
        sva.x = fmaf(p[j], va.x, sva.x); sva.y = fmaf(p[j], va.y, sva.y);
        sva.z = fmaf(p[j], va.z, sva.z); sva.w = fmaf(p[j], va.w, sva.w);
        svb.x = fmaf(p[j], vb.x, svb.x); svb.y = fmaf(p[j], vb.y, svb.y);
        svb.z = fmaf(p[j], vb.z, svb.z); svb.w = fmaf(p[j], vb.w, svb.w);
      }
      acca.x = fmaf(acca.x, corr, sva.x); acca.y = fmaf(acca.y, corr, sva.y);
      acca.z = fmaf(acca.z, corr, sva.z); acca.w = fmaf(acca.w, corr, sva.w);
      accb.x = fmaf(accb.x, corr, svb.x); accb.y = fmaf(accb.y, corr, svb.y);
      accb.z = fmaf(accb.z, corr, svb.z); accb.w = fmaf(accb.w, corr, svb.w);
      m = mn;
    }
  }
  __syncthreads();
  if (lane < 49) {
    float* rp = &vs[((size_t)w*49 + lane)*10];
    rp[0] = m; rp[1] = l;
    rp[2] = acca.x; rp[3] = acca.y; rp[4] = acca.z; rp[5] = acca.w;
    rp[6] = accb.x; rp[7] = accb.y; rp[8] = accb.z; rp[9] = accb.w;
  }
  __syncthreads();
  if (t < 49) {
    float M = -1e30f;
    #pragma unroll
    for (int w4 = 0; w4 < 4; w4++) M = fmaxf(M, vs[(w4*49 + t)*10]);
    float L = 0, a[8] = {0,0,0,0,0,0,0,0};
    #pragma unroll
    for (int w4 = 0; w4 < 4; w4++) {
      const float* rp = &vs[(w4*49 + t)*10];
      float c = __expf(rp[0] - M);
      L += rp[1]*c;
      #pragma unroll
      for (int d = 0; d < 8; d++) a[d] += rp[2+d]*c;
    }
    size_t idx = ((size_t)blk*49 + t)*10;
    part[idx] = M; part[idx+1] = L;
    #pragma unroll
    for (int d = 0; d < 8; d++) part[idx+2+d] = a[d];
  }
}

__global__ void merge_kernel(const float* __restrict__ part, float* __restrict__ gsm){
  int g = blockIdx.x*64 + threadIdx.x;   // 3136
  if (g >= 3136) return;
  int b = g / 392, r = g % 392, nh = r / 49, q = r % 49;
  int blkbase = b*224 + nh*28;
  float M = -1e30f;
  for (int sp = 0; sp < 28; sp++)
    M = fmaxf(M, part[((size_t)(blkbase+sp)*49 + q)*10]);
  float L = 0, a[8] = {0,0,0,0,0,0,0,0};
  for (int sp = 0; sp < 28; sp++) {
    size_t idx = ((size_t)(blkbase+sp)*49 + q)*10;
    float c = __expf(part[idx] - M);
    L += part[idx+1]*c;
    #pragma unroll
    for (int d = 0; d < 8; d++) a[d] += part[idx+2+d]*c;
  }
  #pragma unroll
  for (int d = 0; d < 8; d++)
    gsm[(size_t)(b*49+q)*64 + nh*8 + d] = a[d]/L;
}

// ---------------- xc cols 128..191: bilinear(g) -> bf16 ----------------
__global__ __launch_bounds__(256) void f2_kernel(const float* __restrict__ gsm,
                                                 bf16_t* __restrict__ xc){
  int gidx = blockIdx.x*256 + threadIdx.x;   // N*64 total
  int r = gidx >> 6, cc = gidx & 63;
  int b = r / HW, rem = r % HW, y = rem / 112, x = rem % 112;
  float fy = fminf(fmaxf((y + 0.5f)*0.0625f - 0.5f, 0.f), 6.f);
  float fx = fminf(fmaxf((x + 0.5f)*0.0625f - 0.5f, 0.f), 6.f);
  int y0 = (int)fy, x0 = (int)fx;
  float wy = fy - y0, wx = fx - x0;
  int y1 = y0+1 < 6 ? y0+1 : 6, x1 = x0+1 < 6 ? x0+1 : 6;
  const float* gb = gsm + (size_t)b*49*64 + cc;
  float g00 = gb[(y0*7+x0)*64], g01 = gb[(y0*7+x1)*64];
  float g10 = gb[(y1*7+x0)*64], g11 = gb[(y1*7+x1)*64];
  xc[(size_t)r*256 + 128 + cc] =
      f2b((1-wy)*((1-wx)*g00 + wx*g01) + wy*((1-wx)*g10 + wx*g11));
}

// =====================================================================
extern "C" void kernel_launch(void* const* d_in, const int* in_sizes, int n_in,
                              void* d_out, int out_size, void* d_ws, size_t ws_size,
                              hipStream_t stream) {
  const float* x      = (const float*)d_in[0];
  const float* x_e    = (const float*)d_in[1];
  const float* norm_w = (const float*)d_in[2];
  const float* norm_b = (const float*)d_in[3];
  const float* norme_w= (const float*)d_in[4];
  const float* norme_b= (const float*)d_in[5];
  const float* rr1_w  = (const float*)d_in[6];
  const float* rr1_b  = (const float*)d_in[7];
  const float* rr2_w  = (const float*)d_in[8];
  const float* rr2_b  = (const float*)d_in[9];
  const float* rr3_w  = (const float*)d_in[10];
  const float* rr3_b  = (const float*)d_in[11];
  const float* conv_w = (const float*)d_in[12];
  const float* conv_b = (const float*)d_in[13];
  const float* la1_w  = (const float*)d_in[14];
  const float* la1_b  = (const float*)d_in[15];
  const float* la2_w  = (const float*)d_in[16];
  const float* la2_b  = (const float*)d_in[17];
  const float* lac1_w = (const float*)d_in[18];
  const float* lac1_b = (const float*)d_in[19];
  const float* lac2_w = (const float*)d_in[20];
  const float* lac2_b = (const float*)d_in[21];
  const float* fc1_w  = (const float*)d_in[22];
  const float* fc2_w  = (const float*)d_in[23];
  const float* la3_w  = (const float*)d_in[24];
  const float* la3_b  = (const float*)d_in[25];
  const float* kv_w   = (const float*)d_in[26];
  const float* kv_b   = (const float*)d_in[27];
  const float* q_w    = (const float*)d_in[28];
  const float* q_b    = (const float*)d_in[29];
  const float* proj_w = (const float*)d_in[30];
  const float* proj_b = (const float*)d_in[31];
  const float* proje_w= (const float*)d_in[32];
  const float* proje_b= (const float*)d_in[33];

  const size_t N = N_POS;
  bf16_t* rr1   = (bf16_t*)d_ws;     // N*128 bf16, dead after G3
  bf16_t* xnbuf = rr1 + N*128;       // N*128: xn -> convout
  bf16_t* kvbuf = xnbuf + N*128;     // N*128: kv -> codi
  bf16_t* xcbuf = kvbuf + N*128;     // N*256: [rr2a | rgb | xen/t] -> xc
  float* pool = (float*)(xcbuf + N*256);  // 75264
  float* qbuf = pool + 75264;        // 25088
  float* part = qbuf + 25088;        // 1003520 (uses 878080)
  float* gsm  = part + 1003520;      // 25088
  float* dotb = gsm  + 25088;        // 1024
  float* n1sq = dotb + 1024;         // 8
  float* n2sq = n1sq + 8;            // 1024
  float* attc = n2sq + 1024;         // 1024
  bf16_t* wtab = (bf16_t*)(attc + 1024);  // 135168 shorts

  bf16_t* xn = xnbuf;
  bf16_t* convout = xnbuf;
  bf16_t* kv = kvbuf;
  bf16_t* codi = kvbuf;
  bf16_t* rr2a = xcbuf;
  bf16_t* rgb  = xcbuf + N*128;
  bf16_t* xen  = xcbuf + N*192;
  bf16_t* xc   = xcbuf;
  float* outp = (float*)d_out;
  float* oute = outp + N*128;

  bf16_t* rr1t0 = wtab;            bf16_t* rr1t1 = wtab + 8192;
  bf16_t* rr2t0 = wtab + 16384;    bf16_t* rr2t1 = wtab + 24576;
  bf16_t* la1t  = wtab + 32768;
  bf16_t* kvt0  = wtab + 40960;    bf16_t* kvt1  = wtab + 49152;
  bf16_t* la2t  = wtab + 57344;
  bf16_t* rr3t0 = wtab + 61440;    bf16_t* rr3t1 = wtab + 69632;
  bf16_t* la3t  = wtab + 77824;
  bf16_t* projt0= wtab + 86016;    bf16_t* projt1= wtab + 102400;
  bf16_t* projet= wtab + 118784;

  zero_kernel<<<(75264+255)/256, 256, 0, stream>>>(pool, 75264);
  zero_kernel<<<9, 256, 0, stream>>>(dotb, 2056);
  {
    WJobs js;
    js.j[0]  = {rr1_w,  rr1t0, 128, 128,   0};
    js.j[1]  = {rr1_w,  rr1t1, 128, 128,  64};
    js.j[2]  = {rr2_w,  rr2t0, 128, 128,   0};
    js.j[3]  = {rr2_w,  rr2t1, 128, 128,  64};
    js.j[4]  = {la1_w,  la1t,  128,  64,   0};
    js.j[5]  = {kv_w,   kvt0,  128, 128,   0};
    js.j[6]  = {kv_w,   kvt1,  128, 128,  64};
    js.j[7]  = {la2_w,  la2t,   64,  64,   0};
    js.j[8]  = {rr3_w,  rr3t0, 128, 128,   0};
    js.j[9]  = {rr3_w,  rr3t1, 128, 128,  64};
    js.j[10] = {la3_w,  la3t,  128,  64,   0};
    js.j[11] = {proj_w, projt0,256, 128,   0};
    js.j[12] = {proj_w, projt1,256, 128,  64};
    js.j[13] = {proje_w,projet,256,  64,   0};
    wtrans_kernel<<<14, 256, 0, stream>>>(js);
  }
  ln128_kernel<<<N_POS/4, 256, 0, stream>>>(x, norm_w, norm_b, xn);
  ln64_kernel <<<N_POS/4, 256, 0, stream>>>(x_e, norme_w, norme_b, xen);
  pool_kernel<<<dim3(392,8), 192, 0, stream>>>(xn, xen, pool);
  qproj_kernel<<<392, 64, 0, stream>>>(pool, q_w, q_b, qbuf);
  // G1: xn -> rr1 | rr2a | rgb | kv   (7 tiles, XCD-local)
  {
    MGemmParams p; p.A = xn; p.scale = 0; p.lda = 128; p.K = 128; p.rowsPerB = HW; p.ntiles = 7;
    p.tiles[0] = {rr1t0, rr1_b,    rr1,     0, 128, 0, 0};
    p.tiles[1] = {rr1t1, rr1_b+64, rr1+64,  0, 128, 0, 0};
    p.tiles[2] = {rr2t0, rr2_b,    rr2a,    0, 128, 0, 0};
    p.tiles[3] = {rr2t1, rr2_b+64, rr2a+64, 0, 128, 0, 0};
    p.tiles[4] = {la1t,  la1_b,    rgb,     0,  64, 0, 0};
    p.tiles[5] = {kvt0,  kv_b,     kv,      0, 128, 0, 0};
    p.tiles[6] = {kvt1,  kv_b+64,  kv+64,   0, 128, 0, 0};
    mgemm<<<8*7*98, 256, 0, stream>>>(p);
  }
  attn_kernel<<<1792, 256, 0, stream>>>(qbuf, kv, part);
  merge_kernel<<<49, 64, 0, stream>>>(part, gsm);
  // G2: xen -> t (in-place)
  {
    MGemmParams p; p.A = xen; p.scale = 0; p.lda = 64; p.K = 64; p.rowsPerB = HW; p.ntiles = 1;
    p.tiles[0] = {la2t, la2_b, xen, 0, 64, 0, 0};
    mgemm<<<8*1*98, 256, 0, stream>>>(p);
  }
  dwconv_codi_kernel<<<8*7*14, 256, 0, stream>>>(rgb, xen, lac1_w, lac1_b, lac2_w, lac2_b, codi);
  dwconv128_kernel<<<8*14*14, 256, 0, stream>>>(rr2a, conv_w, conv_b, convout);
  // G3: (convout@rr3 + b) * rr1 -> xc cols 0..127
  {
    MGemmParams p; p.A = convout; p.scale = 0; p.lda = 128; p.K = 128; p.rowsPerB = HW; p.ntiles = 2;
    p.tiles[0] = {rr3t0, rr3_b,    xc,    rr1,    256, 128, 0};
    p.tiles[1] = {rr3t1, rr3_b+64, xc+64, rr1+64, 256, 128, 0};
    mgemm<<<8*2*98, 256, 0, stream>>>(p);
  }
  reduce_kernel<<<392, 256, 0, stream>>>(codi, dotb, n1sq, n2sq);
  attc_kernel<<<8, 128, 0, stream>>>(dotb, n1sq, n2sq, fc1_w, fc2_w, attc);
  // G4: (codi * attc) @ la3 -> xc cols 192..255
  {
    MGemmParams p; p.A = codi; p.scale = attc; p.lda = 128; p.K = 128; p.rowsPerB = HW; p.ntiles = 1;
    p.tiles[0] = {la3t, la3_b, xc + 192, 0, 256, 0, 0};
    mgemm<<<8*1*98, 256, 0, stream>>>(p);
  }
  f2_kernel<<<25088, 256, 0, stream>>>(gsm, xc);
  // G5: xc -> out | out_e (fp32 outputs)
  {
    MGemmParams p; p.A = xc; p.scale = 0; p.lda = 256; p.K = 256; p.rowsPerB = HW; p.ntiles = 3;
    p.tiles[0] = {projt0, proj_b,    outp,    0, 128, 0, 1};
    p.tiles[1] = {projt1, proj_b+64, outp+64, 0, 128, 0, 1};
    p.tiles[2] = {projet, proje_b,   oute,    0,  64, 0, 1};
    mgemm<<<8*3*98, 256, 0, stream>>>(p);
  }
}